// Round 7
// baseline (3950.398 us; speedup 1.0000x reference)
//
#include <hip/hip_runtime.h>
#include <math.h>

#define DEV static __device__ __forceinline__

typedef short s8v  __attribute__((ext_vector_type(8)));   // 8 bf16 (A/B frag)
typedef short s4v  __attribute__((ext_vector_type(4)));
typedef float f4v  __attribute__((ext_vector_type(4)));   // C/D frag

// round-to-nearest-even f32 -> bf16 (bits in a short)
DEV short bf16rne(float f) {
    unsigned u = __float_as_uint(f);
    unsigned r = (u + 0x7fffu + ((u >> 16) & 1u)) >> 16;
    return (short)r;
}

// Exact-IEEE squared distance, same op order as the numpy/XLA reference.
DEV float sqd(float ax, float ay, float az, float bx, float by, float bz) {
    float dx = __fsub_rn(ax, bx), dy = __fsub_rn(ay, by), dz = __fsub_rn(az, bz);
    return __fadd_rn(__fadd_rn(__fmul_rn(dx, dx), __fmul_rn(dy, dy)), __fmul_rn(dz, dz));
}

// ---------------------------------------------------------------------------
// Fused radius top-k + FPS. blockIdx.y < N/4: radius (one wave/query).
// blockIdx.y == N/4: 256-thread FPS for the whole cloud.
//
// FPS round-7 redesign (post-mortem: per-iter was ~2810cyc, est ~900):
//  - winners buffered in LDS, ONE global copy-out at the end (the per-iter
//    global store forced a vmcnt(0) drain at every __syncthreads -> ~300cyc).
//  - per-lane argmax tree (depth log2 P) with coords carried via cndmask.
//  - s_setprio(1): FPS waves win issue arbitration over co-resident radius
//    waves (latency chain vs throughput waves).
// Selection math exact-IEEE fp32; key=(d2_bits<<32)|~j => ties -> lowest j.
// ---------------------------------------------------------------------------
template <int N, int M>
__global__ __launch_bounds__(256) void radius_fps_kernel(
        const float* __restrict__ pos, float rr, int* __restrict__ idx_out,
        int* __restrict__ s_out) {
    __shared__ __align__(16) unsigned long long wkey[2][4];
    __shared__ __align__(16) float wxyz[2][4][4];
    __shared__ int swin[M];
    int b = blockIdx.x;
    const float* p = pos + (size_t)b * N * 3;

    if (blockIdx.y == N / 4) {
        // ---------------- FPS path: 256 threads, 1 barrier/iter ----------------
        __builtin_amdgcn_s_setprio(1);
        constexpr int P = N / 256;
        int tid = threadIdx.x;
        int w = tid >> 6;
        float cx[P], cy[P], cz[P], d[P];
#pragma unroll
        for (int q = 0; q < P; q++) {
            int j = q * 256 + tid;
            cx[q] = p[j * 3 + 0];
            cy[q] = p[j * 3 + 1];
            cz[q] = p[j * 3 + 2];
            d[q] = INFINITY;
        }
        float sx = p[0], sy = p[1], sz = p[2];
        if (tid == 0) swin[0] = 0;
#pragma unroll 1
        for (int m = 1; m < M; m++) {
            // fused d-update; tree argmax with coords carried via cndmask
            float v[P], X[P], Y[P], Z[P];
            unsigned ji[P];
#pragma unroll
            for (int q = 0; q < P; q++) {
                float di = sqd(cx[q], cy[q], cz[q], sx, sy, sz);
                float dn = fminf(d[q], di);
                d[q] = dn;
                v[q] = dn;
                ji[q] = (unsigned)(q * 256 + tid);
                X[q] = cx[q]; Y[q] = cy[q]; Z[q] = cz[q];
            }
#pragma unroll
            for (int s = P / 2; s >= 1; s >>= 1) {
#pragma unroll
                for (int t = 0; t < s; t++) {
                    bool take = v[t + s] > v[t];   // strict >: lower q (lower j) kept
                    v[t]  = take ? v[t + s]  : v[t];
                    ji[t] = take ? ji[t + s] : ji[t];
                    X[t]  = take ? X[t + s]  : X[t];
                    Y[t]  = take ? Y[t + s]  : Y[t];
                    Z[t]  = take ? Z[t + s]  : Z[t];
                }
            }
            unsigned long long key =
                (((unsigned long long)__float_as_uint(v[0])) << 32)
                | (unsigned)(0xFFFFFFFFu - ji[0]);
            unsigned long long kr = key;
#pragma unroll
            for (int off = 1; off < 64; off <<= 1) {
                unsigned long long o = __shfl_xor(kr, off, 64);
                kr = (o > kr) ? o : kr;
            }
            int par = m & 1;
            if (key == kr) {               // unique winner lane of this wave
                wkey[par][w] = kr;
                f4v cv; cv[0] = X[0]; cv[1] = Y[0]; cv[2] = Z[0]; cv[3] = 0.f;
                *(f4v*)&wxyz[par][w][0] = cv;
            }
            __syncthreads();
            unsigned long long k0 = wkey[par][0], k1 = wkey[par][1];
            unsigned long long k2 = wkey[par][2], k3 = wkey[par][3];
            f4v c0 = *(const f4v*)&wxyz[par][0][0];
            f4v c1 = *(const f4v*)&wxyz[par][1][0];
            f4v c2 = *(const f4v*)&wxyz[par][2][0];
            f4v c3 = *(const f4v*)&wxyz[par][3][0];
            bool a01 = k1 > k0;
            unsigned long long k01 = a01 ? k1 : k0;
            f4v c01 = a01 ? c1 : c0;
            bool a23 = k3 > k2;
            unsigned long long k23 = a23 ? k3 : k2;
            f4v c23 = a23 ? c3 : c2;
            bool af = k23 > k01;
            unsigned long long kf = af ? k23 : k01;
            f4v cf = af ? c23 : c01;
            sx = cf[0]; sy = cf[1]; sz = cf[2];
            if (tid == 0)
                swin[m] = (int)(0xFFFFFFFFu - (unsigned)(kf & 0xFFFFFFFFull));
        }
        __syncthreads();
        int* so = s_out + b * M;
        for (int j = tid; j < M; j += 256) so[j] = swin[j];
        return;
    }

    // ---------------- radius top-k path: one wave per query ----------------
    constexpr int Q = N / 64;
    constexpr unsigned long long INV = ~0ull;
    int wid = threadIdx.x >> 6, lane = threadIdx.x & 63;
    int i = blockIdx.y * 4 + wid;
    float qx = p[i * 3 + 0], qy = p[i * 3 + 1], qz = p[i * 3 + 2];

    unsigned long long c[Q];
#pragma unroll
    for (int q = 0; q < Q; q++) {
        int jj = q * 64 + lane;
        float px = p[jj * 3 + 0], py = p[jj * 3 + 1], pz = p[jj * 3 + 2];
        float d2 = sqd(px, py, pz, qx, qy, qz);
        bool valid = (jj != i) && (d2 <= rr);
        c[q] = valid ? ((((unsigned long long)__float_as_uint(d2)) << 32)
                        | (unsigned)jj)
                     : INV;
    }

#pragma unroll
    for (int k = 2; k <= Q; k <<= 1) {
#pragma unroll
        for (int jj = k >> 1; jj > 0; jj >>= 1) {
#pragma unroll
            for (int t = 0; t < Q; t++) {
                int l = t ^ jj;
                if (l > t) {
                    bool up = ((t & k) == 0);
                    unsigned long long a = c[t], d = c[l];
                    bool sw = (a > d) != up;
                    c[t] = sw ? d : a;
                    c[l] = sw ? a : d;
                }
            }
        }
    }

    int* orow = idx_out + ((size_t)b * N + i) * 33;
    int cnt = 0;
    for (int s = 0; s < 32; s++) {
        unsigned long long h = c[0];
        unsigned long long g = h;
#pragma unroll
        for (int off = 1; off < 64; off <<= 1) {
            unsigned long long o = __shfl_xor(g, off, 64);
            g = (o < g) ? o : g;
        }
        if (lane == 0) orow[s] = (int)(unsigned)(g & 0xffffffffull);
        cnt += (g != INV) ? 1 : 0;
        if (h == g && g != INV) {
#pragma unroll
            for (int q = 0; q < Q - 1; q++) c[q] = c[q + 1];
            c[Q - 1] = INV;
        }
    }
    if (lane == 0) {
        if (cnt < 32) orow[cnt] = i;
        orow[32] = (cnt == 32) ? i : -1;
    }
}

// ---------------------------------------------------------------------------
// Plain radius top-k (stage 3, no FPS needed).
// ---------------------------------------------------------------------------
template <int N>
__global__ __launch_bounds__(256) void radius_topk_kernel(
        const float* __restrict__ pos, float rr, int* __restrict__ idx_out) {
    constexpr int Q = N / 64;
    constexpr unsigned long long INV = ~0ull;
    int b = blockIdx.x;
    int wid = threadIdx.x >> 6, lane = threadIdx.x & 63;
    int i = blockIdx.y * 4 + wid;
    const float* p = pos + (size_t)b * N * 3;
    float qx = p[i * 3 + 0], qy = p[i * 3 + 1], qz = p[i * 3 + 2];

    unsigned long long c[Q];
#pragma unroll
    for (int q = 0; q < Q; q++) {
        int jj = q * 64 + lane;
        float px = p[jj * 3 + 0], py = p[jj * 3 + 1], pz = p[jj * 3 + 2];
        float d2 = sqd(px, py, pz, qx, qy, qz);
        bool valid = (jj != i) && (d2 <= rr);
        c[q] = valid ? ((((unsigned long long)__float_as_uint(d2)) << 32)
                        | (unsigned)jj)
                     : INV;
    }

#pragma unroll
    for (int k = 2; k <= Q; k <<= 1) {
#pragma unroll
        for (int jj = k >> 1; jj > 0; jj >>= 1) {
#pragma unroll
            for (int t = 0; t < Q; t++) {
                int l = t ^ jj;
                if (l > t) {
                    bool up = ((t & k) == 0);
                    unsigned long long a = c[t], d = c[l];
                    bool sw = (a > d) != up;
                    c[t] = sw ? d : a;
                    c[l] = sw ? a : d;
                }
            }
        }
    }

    int* orow = idx_out + ((size_t)b * N + i) * 33;
    int cnt = 0;
    for (int s = 0; s < 32; s++) {
        unsigned long long h = c[0];
        unsigned long long g = h;
#pragma unroll
        for (int off = 1; off < 64; off <<= 1) {
            unsigned long long o = __shfl_xor(g, off, 64);
            g = (o < g) ? o : g;
        }
        if (lane == 0) orow[s] = (int)(unsigned)(g & 0xffffffffull);
        cnt += (g != INV) ? 1 : 0;
        if (h == g && g != INV) {
#pragma unroll
            for (int q = 0; q < Q - 1; q++) c[q] = c[q + 1];
            c[Q - 1] = INV;
        }
    }
    if (lane == 0) {
        if (cnt < 32) orow[cnt] = i;
        orow[32] = (cnt == 32) ? i : -1;
    }
}

// ---------------------------------------------------------------------------
// Weight pre-pack (unchanged).
// ---------------------------------------------------------------------------
__global__ void pack_w_kernel(const float* __restrict__ W, short* __restrict__ out,
                              int Kreal, int C, int KS, int total) {
    int t = blockIdx.x * 256 + threadIdx.x;
    if (t >= total) return;
    int lane = t & 63;
    int mk = t >> 6;
    int ks = mk % KS, mt = mk / KS;
    int c = 16 * mt + (lane & 15);
    int k0 = 32 * ks + ((lane >> 4) << 3);
    s8v v;
#pragma unroll
    for (int j = 0; j < 8; j++) {
        int k = k0 + j;
        v[j] = (k < Kreal) ? bf16rne(W[(size_t)k * C + c]) : (short)0;
    }
    *(s8v*)(out + (size_t)t * 8) = v;
}

// ---------------------------------------------------------------------------
// Fused MFMA point-conv (unchanged).
// ---------------------------------------------------------------------------
template <int CXIN, int CH, int PPB, int N>
__global__ __launch_bounds__(256) void conv_mfma_kernel(
        const float* __restrict__ pos, const float* __restrict__ xin,
        const int* __restrict__ idx,
        const short* __restrict__ Wpa, const float* __restrict__ ba,
        const short* __restrict__ Wpb, const float* __restrict__ bb,
        float* __restrict__ xout) {
    constexpr int CIN  = CXIN + 3;
    constexpr int CINp = (CIN + 31) & ~31;
    constexpr int KS1  = CINp / 32, KS2 = CH / 32;
    constexpr int MT   = CH / 16;
    constexpr int MTW  = (PPB == 4) ? MT : MT / 4;
    constexpr int RP   = 48;
    constexpr int NT   = 3;
    constexpr int FS   = CINp * 2 + 16;
    constexpr int HS   = CH * 2 + 16;
    __shared__ __align__(16) char Fs[PPB * RP * FS];
    __shared__ __align__(16) char Hs[PPB * RP * HS];
    __shared__ int sj[PPB * RP];

    int tid = threadIdx.x;
    int lane = tid & 63, wid = tid >> 6;
    int pid0 = blockIdx.x * PPB;

    for (int r = tid; r < PPB * RP; r += 256) {
        int p = r / RP, s = r - p * RP;
        sj[r] = (s < 33) ? idx[(size_t)(pid0 + p) * 33 + s] : -1;
    }
    __syncthreads();

    constexpr int FE = PPB * RP * CINp;
    for (int e = tid; e < FE; e += 256) {
        int r = e / CINp, f = e - r * CINp;
        int p = r / RP;
        int pid = pid0 + p;
        int b = pid / N, i = pid - b * N;
        int j = sj[r];
        float v = 0.f;
        if (j >= 0 && f < CIN) {
            if (f < CXIN) {
                v = xin[((size_t)b * N + j) * CXIN + f];
            } else {
                int a = f - CXIN;
                v = __fsub_rn(pos[((size_t)b * N + j) * 3 + a],
                              pos[((size_t)b * N + i) * 3 + a]);
            }
        }
        *(short*)(Fs + (size_t)r * FS + f * 2) = bf16rne(v);
    }
    __syncthreads();

    int pw  = (PPB == 4) ? wid : 0;
    int mt0 = (PPB == 4) ? 0 : wid * MTW;
    const char* Fw = Fs + pw * RP * FS;
    char* Hw = Hs + pw * RP * HS;
    int lr = lane & 15, lg = lane >> 4;

    f4v acc[MTW][NT];
#pragma unroll
    for (int m = 0; m < MTW; m++)
#pragma unroll
        for (int nt = 0; nt < NT; nt++)
#pragma unroll
            for (int q = 0; q < 4; q++) acc[m][nt][q] = 0.f;
#pragma unroll
    for (int ks = 0; ks < KS1; ks++) {
        s8v bfr[NT];
#pragma unroll
        for (int nt = 0; nt < NT; nt++)
            bfr[nt] = *(const s8v*)(Fw + (nt * 16 + lr) * FS + (32 * ks + lg * 8) * 2);
#pragma unroll
        for (int m = 0; m < MTW; m++) {
            s8v afr = *(const s8v*)(Wpa + (((size_t)(mt0 + m) * KS1 + ks) * 64 + lane) * 8);
#pragma unroll
            for (int nt = 0; nt < NT; nt++)
                acc[m][nt] = __builtin_amdgcn_mfma_f32_16x16x32_bf16(afr, bfr[nt], acc[m][nt], 0, 0, 0);
        }
    }
#pragma unroll
    for (int m = 0; m < MTW; m++) {
        int cbase = (mt0 + m) * 16 + lg * 4;
        f4v bv = *(const f4v*)(ba + cbase);
#pragma unroll
        for (int nt = 0; nt < NT; nt++) {
            s4v hq;
#pragma unroll
            for (int q = 0; q < 4; q++)
                hq[q] = bf16rne(fmaxf(acc[m][nt][q] + bv[q], 0.f));
            *(s4v*)(Hw + (nt * 16 + lr) * HS + cbase * 2) = hq;
        }
    }
    __syncthreads();

    f4v acc2[MTW][NT];
#pragma unroll
    for (int m = 0; m < MTW; m++)
#pragma unroll
        for (int nt = 0; nt < NT; nt++)
#pragma unroll
            for (int q = 0; q < 4; q++) acc2[m][nt][q] = 0.f;
#pragma unroll
    for (int ks = 0; ks < KS2; ks++) {
        s8v bfr[NT];
#pragma unroll
        for (int nt = 0; nt < NT; nt++)
            bfr[nt] = *(const s8v*)(Hw + (nt * 16 + lr) * HS + (32 * ks + lg * 8) * 2);
#pragma unroll
        for (int m = 0; m < MTW; m++) {
            s8v afr = *(const s8v*)(Wpb + (((size_t)(mt0 + m) * KS2 + ks) * 64 + lane) * 8);
#pragma unroll
            for (int nt = 0; nt < NT; nt++)
                acc2[m][nt] = __builtin_amdgcn_mfma_f32_16x16x32_bf16(afr, bfr[nt], acc2[m][nt], 0, 0, 0);
        }
    }

    const int* sjw = sj + pw * RP;
#pragma unroll
    for (int m = 0; m < MTW; m++) {
        int cbase = (mt0 + m) * 16 + lg * 4;
        f4v bv = *(const f4v*)(bb + cbase);
        f4v vmx;
#pragma unroll
        for (int q = 0; q < 4; q++) vmx[q] = 0.f;
#pragma unroll
        for (int nt = 0; nt < NT; nt++) {
            int s = nt * 16 + lr;
            bool valid = (s < 33) && (sjw[s] >= 0);
#pragma unroll
            for (int q = 0; q < 4; q++) {
                float v = fmaxf(acc2[m][nt][q] + bv[q], 0.f);
                if (valid) vmx[q] = fmaxf(vmx[q], v);
            }
        }
#pragma unroll
        for (int off = 1; off < 16; off <<= 1)
#pragma unroll
            for (int q = 0; q < 4; q++)
                vmx[q] = fmaxf(vmx[q], __shfl_xor(vmx[q], off, 64));
        if (lr == 0) {
            int pid = pid0 + pw;
            *(f4v*)(xout + (size_t)pid * CH + cbase) = vmx;
        }
    }
}

// ---------------------------------------------------------------------------
__global__ void gather_kernel(
        const float* __restrict__ pos_in, const float* __restrict__ x_in,
        const int* __restrict__ s, int Nin, int M, int C,
        float* __restrict__ pos_out, float* __restrict__ x_out) {
    int b = blockIdx.y, m = blockIdx.x, t = threadIdx.x;
    int j = s[b * M + m];
    x_out[((size_t)b * M + m) * C + t] = x_in[((size_t)b * Nin + j) * C + t];
    if (t < 3) pos_out[((size_t)b * M + m) * 3 + t] = pos_in[((size_t)b * Nin + j) * 3 + t];
}

// ---------------------------------------------------------------------------
// Global max pool + MLP head + log_softmax (unchanged).
// ---------------------------------------------------------------------------
__global__ __launch_bounds__(256) void head_kernel(
        const float* __restrict__ x3,
        const float* __restrict__ Wl1, const float* __restrict__ bl1,
        const float* __restrict__ Wl2, const float* __restrict__ bl2,
        const float* __restrict__ Wl3, const float* __restrict__ bl3,
        float* __restrict__ out) {
    __shared__ float gbuf[256], h1[256], h2[256], h3[40];
    int b = blockIdx.x, c = threadIdx.x;
    const float* xb = x3 + (size_t)b * 256 * 256;
    float m = -INFINITY;
    for (int r = 0; r < 256; r++) m = fmaxf(m, xb[r * 256 + c]);
    gbuf[c] = m;
    __syncthreads();
    float a = bl1[c];
    for (int k = 0; k < 256; k++) a = fmaf(gbuf[k], Wl1[k * 256 + c], a);
    h1[c] = fmaxf(a, 0.f);
    __syncthreads();
    a = bl2[c];
    for (int k = 0; k < 256; k++) a = fmaf(h1[k], Wl2[k * 256 + c], a);
    h2[c] = fmaxf(a, 0.f);
    __syncthreads();
    if (c < 40) {
        a = bl3[c];
        for (int k = 0; k < 256; k++) a = fmaf(h2[k], Wl3[k * 40 + c], a);
        h3[c] = a;
    }
    __syncthreads();
    if (c < 64) {
        float v = -INFINITY;
        if (c < 40) v = h3[c];
        float mx = v;
#pragma unroll
        for (int off = 32; off >= 1; off >>= 1) mx = fmaxf(mx, __shfl_xor(mx, off, 64));
        float e = (c < 40) ? expf(__fsub_rn(v, mx)) : 0.f;
        float s = e;
#pragma unroll
        for (int off = 32; off >= 1; off >>= 1) s = __fadd_rn(s, __shfl_xor(s, off, 64));
        float ls = logf(s);
        if (c < 40) out[b * 40 + c] = __fsub_rn(__fsub_rn(v, mx), ls);
    }
}

// ---------------------------------------------------------------------------
extern "C" void kernel_launch(void* const* d_in, const int* in_sizes, int n_in,
                              void* d_out, int out_size, void* d_ws, size_t ws_size,
                              hipStream_t stream) {
    (void)in_sizes; (void)n_in; (void)out_size; (void)ws_size;
    const float* pos = (const float*)d_in[0];
    const float* W1a = (const float*)d_in[2];
    const float* b1a = (const float*)d_in[3];
    const float* W1b = (const float*)d_in[4];
    const float* b1b = (const float*)d_in[5];
    const float* W2a = (const float*)d_in[6];
    const float* b2a = (const float*)d_in[7];
    const float* W2b = (const float*)d_in[8];
    const float* b2b = (const float*)d_in[9];
    const float* W3a = (const float*)d_in[10];
    const float* b3a = (const float*)d_in[11];
    const float* W3b = (const float*)d_in[12];
    const float* b3b = (const float*)d_in[13];
    const float* Wl1 = (const float*)d_in[14];
    const float* bl1 = (const float*)d_in[15];
    const float* Wl2 = (const float*)d_in[16];
    const float* bl2 = (const float*)d_in[17];
    const float* Wl3 = (const float*)d_in[18];
    const float* bl3 = (const float*)d_in[19];
    float* out = (float*)d_out;

    const int B = 32;
    char* w = (char*)d_ws;
    auto alloc = [&](size_t bytes) -> char* {
        char* r = w;
        w += (bytes + 255) & ~(size_t)255;
        return r;
    };
    int*   idx1 = (int*)  alloc((size_t)B * 2048 * 33 * 4);
    float* x1   = (float*)alloc((size_t)B * 2048 * 64 * 4);
    int*   s1   = (int*)  alloc((size_t)B * 1024 * 4);
    float* pos2 = (float*)alloc((size_t)B * 1024 * 3 * 4);
    float* x2in = (float*)alloc((size_t)B * 1024 * 64 * 4);
    int*   idx2 = (int*)  alloc((size_t)B * 1024 * 33 * 4);
    float* x2   = (float*)alloc((size_t)B * 1024 * 128 * 4);
    int*   s2   = (int*)  alloc((size_t)B * 256 * 4);
    float* pos3 = (float*)alloc((size_t)B * 256 * 3 * 4);
    float* x3in = (float*)alloc((size_t)B * 256 * 128 * 4);
    int*   idx3 = (int*)  alloc((size_t)B * 256 * 33 * 4);
    float* x3   = (float*)alloc((size_t)B * 256 * 256 * 4);
    short* Wp1a = (short*)alloc(4  * 1 * 64 * 8 * 2);
    short* Wp1b = (short*)alloc(4  * 2 * 64 * 8 * 2);
    short* Wp2a = (short*)alloc(8  * 3 * 64 * 8 * 2);
    short* Wp2b = (short*)alloc(8  * 4 * 64 * 8 * 2);
    short* Wp3a = (short*)alloc(16 * 5 * 64 * 8 * 2);
    short* Wp3b = (short*)alloc(16 * 8 * 64 * 8 * 2);

    pack_w_kernel<<<1,  256, 0, stream>>>(W1a, Wp1a, 3,   64,  1, 256);
    pack_w_kernel<<<2,  256, 0, stream>>>(W1b, Wp1b, 64,  64,  2, 512);
    pack_w_kernel<<<6,  256, 0, stream>>>(W2a, Wp2a, 67,  128, 3, 1536);
    pack_w_kernel<<<8,  256, 0, stream>>>(W2b, Wp2b, 128, 128, 4, 2048);
    pack_w_kernel<<<20, 256, 0, stream>>>(W3a, Wp3a, 131, 256, 5, 5120);
    pack_w_kernel<<<32, 256, 0, stream>>>(W3b, Wp3b, 256, 256, 8, 8192);

    // ---- SA module 1 (2048 pts, r=0.2): radius + FPS fused (independent) ----
    radius_fps_kernel<2048, 1024><<<dim3(B, 513), 256, 0, stream>>>(
        pos, 0.04f, idx1, s1);
    conv_mfma_kernel<0, 64, 4, 2048><<<B * 2048 / 4, 256, 0, stream>>>(
        pos, nullptr, idx1, Wp1a, b1a, Wp1b, b1b, x1);
    gather_kernel<<<dim3(1024, B), 64, 0, stream>>>(pos, x1, s1, 2048, 1024, 64, pos2, x2in);

    // ---- SA module 2 (1024 pts, r=0.4): radius + FPS fused ----
    radius_fps_kernel<1024, 256><<<dim3(B, 257), 256, 0, stream>>>(
        pos2, 0.16f, idx2, s2);
    conv_mfma_kernel<64, 128, 1, 1024><<<B * 1024, 256, 0, stream>>>(
        pos2, x2in, idx2, Wp2a, b2a, Wp2b, b2b, x2);
    gather_kernel<<<dim3(256, B), 128, 0, stream>>>(pos2, x2, s2, 1024, 256, 128, pos3, x3in);

    // ---- SA module 3 (256 pts, r=1.0) ----
    radius_topk_kernel<256><<<dim3(B, 64), 256, 0, stream>>>(pos3, 1.0f, idx3);
    conv_mfma_kernel<128, 256, 1, 256><<<B * 256, 256, 0, stream>>>(
        pos3, x3in, idx3, Wp3a, b3a, Wp3b, b3b, x3);

    // ---- global pool + head ----
    head_kernel<<<B, 256, 0, stream>>>(x3, Wl1, bl1, Wl2, bl2, Wl3, bl3, out);
}

// Round 8
// 2225.553 us; speedup vs baseline: 1.7750x; 1.7750x over previous
//
#include <hip/hip_runtime.h>
#include <math.h>

#define DEV static __device__ __forceinline__

typedef short s8v  __attribute__((ext_vector_type(8)));   // 8 bf16 (A/B frag)
typedef short s4v  __attribute__((ext_vector_type(4)));
typedef float f4v  __attribute__((ext_vector_type(4)));   // C/D frag

// round-to-nearest-even f32 -> bf16 (bits in a short)
DEV short bf16rne(float f) {
    unsigned u = __float_as_uint(f);
    unsigned r = (u + 0x7fffu + ((u >> 16) & 1u)) >> 16;
    return (short)r;
}

// Exact-IEEE squared distance, same op order as the numpy/XLA reference.
DEV float sqd(float ax, float ay, float az, float bx, float by, float bz) {
    float dx = __fsub_rn(ax, bx), dy = __fsub_rn(ay, by), dz = __fsub_rn(az, bz);
    return __fadd_rn(__fadd_rn(__fmul_rn(dx, dx), __fmul_rn(dy, dy)), __fmul_rn(dz, dz));
}

// ---------------------------------------------------------------------------
// Fused radius top-k + FPS. blockIdx.y < N/4: radius (one wave/query).
// blockIdx.y == N/4: 256-thread FPS for the whole cloud.
//
// FPS = round-6 structure (fused serial argmax, small live set — the round-7
// tree argmax pushed live VGPRs past the allocation and spilled the loop to
// scratch: 2.4x regression) + ONE change: winners buffered in LDS swin[],
// single coalesced global copy-out at the end. This removes the per-iter
// global store whose vmcnt(0) drain at every __syncthreads cost ~300-600cyc.
// Selection math exact-IEEE fp32; key=(d2_bits<<32)|~j => ties -> lowest j.
// ---------------------------------------------------------------------------
template <int N, int M>
__global__ __launch_bounds__(256) void radius_fps_kernel(
        const float* __restrict__ pos, float rr, int* __restrict__ idx_out,
        int* __restrict__ s_out) {
    __shared__ __align__(16) unsigned long long wkey[2][4];
    __shared__ __align__(16) float wxyz[2][4][4];
    __shared__ int swin[M];
    int b = blockIdx.x;
    const float* p = pos + (size_t)b * N * 3;

    if (blockIdx.y == N / 4) {
        // ---------------- FPS path: 256 threads, 1 barrier/iter ----------------
        constexpr int P = N / 256;
        int tid = threadIdx.x;
        int w = tid >> 6;
        float cx[P], cy[P], cz[P], d[P];
#pragma unroll
        for (int q = 0; q < P; q++) {
            int j = q * 256 + tid;
            cx[q] = p[j * 3 + 0];
            cy[q] = p[j * 3 + 1];
            cz[q] = p[j * 3 + 2];
            d[q] = INFINITY;
        }
        float sx = p[0], sy = p[1], sz = p[2];
        if (tid == 0) swin[0] = 0;
#pragma unroll 1
        for (int m = 1; m < M; m++) {
            // fused d-update + serial argmax scan (small live set: 5 values)
            float best = -INFINITY, bx = 0.f, by = 0.f, bz = 0.f;
            int bj = 0;
#pragma unroll
            for (int q = 0; q < P; q++) {
                float di = sqd(cx[q], cy[q], cz[q], sx, sy, sz);
                float dn = fminf(d[q], di);
                d[q] = dn;
                bool take = dn > best;     // strict >, q asc => lowest j in lane
                best = take ? dn : best;
                bj = take ? (q * 256 + tid) : bj;
                bx = take ? cx[q] : bx;
                by = take ? cy[q] : by;
                bz = take ? cz[q] : bz;
            }
            unsigned long long key =
                (((unsigned long long)__float_as_uint(best)) << 32)
                | (unsigned)(0xFFFFFFFFu - (unsigned)bj);
            unsigned long long kr = key;
#pragma unroll
            for (int off = 1; off < 64; off <<= 1) {
                unsigned long long o = __shfl_xor(kr, off, 64);
                kr = (o > kr) ? o : kr;
            }
            int par = m & 1;
            if (key == kr) {               // unique winner lane of this wave
                wkey[par][w] = kr;
                f4v cv; cv[0] = bx; cv[1] = by; cv[2] = bz; cv[3] = 0.f;
                *(f4v*)&wxyz[par][w][0] = cv;
            }
            __syncthreads();
            unsigned long long k0 = wkey[par][0], k1 = wkey[par][1];
            unsigned long long k2 = wkey[par][2], k3 = wkey[par][3];
            f4v c0 = *(const f4v*)&wxyz[par][0][0];
            f4v c1 = *(const f4v*)&wxyz[par][1][0];
            f4v c2 = *(const f4v*)&wxyz[par][2][0];
            f4v c3 = *(const f4v*)&wxyz[par][3][0];
            bool a01 = k1 > k0;
            unsigned long long k01 = a01 ? k1 : k0;
            f4v c01 = a01 ? c1 : c0;
            bool a23 = k3 > k2;
            unsigned long long k23 = a23 ? k3 : k2;
            f4v c23 = a23 ? c3 : c2;
            bool af = k23 > k01;
            unsigned long long kf = af ? k23 : k01;
            f4v cf = af ? c23 : c01;
            sx = cf[0]; sy = cf[1]; sz = cf[2];
            if (tid == 0)
                swin[m] = (int)(0xFFFFFFFFu - (unsigned)(kf & 0xFFFFFFFFull));
        }
        __syncthreads();
        int* so = s_out + b * M;
        for (int j = tid; j < M; j += 256) so[j] = swin[j];
        return;
    }

    // ---------------- radius top-k path: one wave per query ----------------
    constexpr int Q = N / 64;
    constexpr unsigned long long INV = ~0ull;
    int wid = threadIdx.x >> 6, lane = threadIdx.x & 63;
    int i = blockIdx.y * 4 + wid;
    float qx = p[i * 3 + 0], qy = p[i * 3 + 1], qz = p[i * 3 + 2];

    unsigned long long c[Q];
#pragma unroll
    for (int q = 0; q < Q; q++) {
        int jj = q * 64 + lane;
        float px = p[jj * 3 + 0], py = p[jj * 3 + 1], pz = p[jj * 3 + 2];
        float d2 = sqd(px, py, pz, qx, qy, qz);
        bool valid = (jj != i) && (d2 <= rr);
        c[q] = valid ? ((((unsigned long long)__float_as_uint(d2)) << 32)
                        | (unsigned)jj)
                     : INV;
    }

#pragma unroll
    for (int k = 2; k <= Q; k <<= 1) {
#pragma unroll
        for (int jj = k >> 1; jj > 0; jj >>= 1) {
#pragma unroll
            for (int t = 0; t < Q; t++) {
                int l = t ^ jj;
                if (l > t) {
                    bool up = ((t & k) == 0);
                    unsigned long long a = c[t], d = c[l];
                    bool sw = (a > d) != up;
                    c[t] = sw ? d : a;
                    c[l] = sw ? a : d;
                }
            }
        }
    }

    int* orow = idx_out + ((size_t)b * N + i) * 33;
    int cnt = 0;
    for (int s = 0; s < 32; s++) {
        unsigned long long h = c[0];
        unsigned long long g = h;
#pragma unroll
        for (int off = 1; off < 64; off <<= 1) {
            unsigned long long o = __shfl_xor(g, off, 64);
            g = (o < g) ? o : g;
        }
        if (lane == 0) orow[s] = (int)(unsigned)(g & 0xffffffffull);
        cnt += (g != INV) ? 1 : 0;
        if (h == g && g != INV) {
#pragma unroll
            for (int q = 0; q < Q - 1; q++) c[q] = c[q + 1];
            c[Q - 1] = INV;
        }
    }
    if (lane == 0) {
        if (cnt < 32) orow[cnt] = i;
        orow[32] = (cnt == 32) ? i : -1;
    }
}

// ---------------------------------------------------------------------------
// Plain radius top-k (stage 3, no FPS needed).
// ---------------------------------------------------------------------------
template <int N>
__global__ __launch_bounds__(256) void radius_topk_kernel(
        const float* __restrict__ pos, float rr, int* __restrict__ idx_out) {
    constexpr int Q = N / 64;
    constexpr unsigned long long INV = ~0ull;
    int b = blockIdx.x;
    int wid = threadIdx.x >> 6, lane = threadIdx.x & 63;
    int i = blockIdx.y * 4 + wid;
    const float* p = pos + (size_t)b * N * 3;
    float qx = p[i * 3 + 0], qy = p[i * 3 + 1], qz = p[i * 3 + 2];

    unsigned long long c[Q];
#pragma unroll
    for (int q = 0; q < Q; q++) {
        int jj = q * 64 + lane;
        float px = p[jj * 3 + 0], py = p[jj * 3 + 1], pz = p[jj * 3 + 2];
        float d2 = sqd(px, py, pz, qx, qy, qz);
        bool valid = (jj != i) && (d2 <= rr);
        c[q] = valid ? ((((unsigned long long)__float_as_uint(d2)) << 32)
                        | (unsigned)jj)
                     : INV;
    }

#pragma unroll
    for (int k = 2; k <= Q; k <<= 1) {
#pragma unroll
        for (int jj = k >> 1; jj > 0; jj >>= 1) {
#pragma unroll
            for (int t = 0; t < Q; t++) {
                int l = t ^ jj;
                if (l > t) {
                    bool up = ((t & k) == 0);
                    unsigned long long a = c[t], d = c[l];
                    bool sw = (a > d) != up;
                    c[t] = sw ? d : a;
                    c[l] = sw ? a : d;
                }
            }
        }
    }

    int* orow = idx_out + ((size_t)b * N + i) * 33;
    int cnt = 0;
    for (int s = 0; s < 32; s++) {
        unsigned long long h = c[0];
        unsigned long long g = h;
#pragma unroll
        for (int off = 1; off < 64; off <<= 1) {
            unsigned long long o = __shfl_xor(g, off, 64);
            g = (o < g) ? o : g;
        }
        if (lane == 0) orow[s] = (int)(unsigned)(g & 0xffffffffull);
        cnt += (g != INV) ? 1 : 0;
        if (h == g && g != INV) {
#pragma unroll
            for (int q = 0; q < Q - 1; q++) c[q] = c[q + 1];
            c[Q - 1] = INV;
        }
    }
    if (lane == 0) {
        if (cnt < 32) orow[cnt] = i;
        orow[32] = (cnt == 32) ? i : -1;
    }
}

// ---------------------------------------------------------------------------
// Weight pre-pack (unchanged).
// ---------------------------------------------------------------------------
__global__ void pack_w_kernel(const float* __restrict__ W, short* __restrict__ out,
                              int Kreal, int C, int KS, int total) {
    int t = blockIdx.x * 256 + threadIdx.x;
    if (t >= total) return;
    int lane = t & 63;
    int mk = t >> 6;
    int ks = mk % KS, mt = mk / KS;
    int c = 16 * mt + (lane & 15);
    int k0 = 32 * ks + ((lane >> 4) << 3);
    s8v v;
#pragma unroll
    for (int j = 0; j < 8; j++) {
        int k = k0 + j;
        v[j] = (k < Kreal) ? bf16rne(W[(size_t)k * C + c]) : (short)0;
    }
    *(s8v*)(out + (size_t)t * 8) = v;
}

// ---------------------------------------------------------------------------
// Fused MFMA point-conv (unchanged).
// ---------------------------------------------------------------------------
template <int CXIN, int CH, int PPB, int N>
__global__ __launch_bounds__(256) void conv_mfma_kernel(
        const float* __restrict__ pos, const float* __restrict__ xin,
        const int* __restrict__ idx,
        const short* __restrict__ Wpa, const float* __restrict__ ba,
        const short* __restrict__ Wpb, const float* __restrict__ bb,
        float* __restrict__ xout) {
    constexpr int CIN  = CXIN + 3;
    constexpr int CINp = (CIN + 31) & ~31;
    constexpr int KS1  = CINp / 32, KS2 = CH / 32;
    constexpr int MT   = CH / 16;
    constexpr int MTW  = (PPB == 4) ? MT : MT / 4;
    constexpr int RP   = 48;
    constexpr int NT   = 3;
    constexpr int FS   = CINp * 2 + 16;
    constexpr int HS   = CH * 2 + 16;
    __shared__ __align__(16) char Fs[PPB * RP * FS];
    __shared__ __align__(16) char Hs[PPB * RP * HS];
    __shared__ int sj[PPB * RP];

    int tid = threadIdx.x;
    int lane = tid & 63, wid = tid >> 6;
    int pid0 = blockIdx.x * PPB;

    for (int r = tid; r < PPB * RP; r += 256) {
        int p = r / RP, s = r - p * RP;
        sj[r] = (s < 33) ? idx[(size_t)(pid0 + p) * 33 + s] : -1;
    }
    __syncthreads();

    constexpr int FE = PPB * RP * CINp;
    for (int e = tid; e < FE; e += 256) {
        int r = e / CINp, f = e - r * CINp;
        int p = r / RP;
        int pid = pid0 + p;
        int b = pid / N, i = pid - b * N;
        int j = sj[r];
        float v = 0.f;
        if (j >= 0 && f < CIN) {
            if (f < CXIN) {
                v = xin[((size_t)b * N + j) * CXIN + f];
            } else {
                int a = f - CXIN;
                v = __fsub_rn(pos[((size_t)b * N + j) * 3 + a],
                              pos[((size_t)b * N + i) * 3 + a]);
            }
        }
        *(short*)(Fs + (size_t)r * FS + f * 2) = bf16rne(v);
    }
    __syncthreads();

    int pw  = (PPB == 4) ? wid : 0;
    int mt0 = (PPB == 4) ? 0 : wid * MTW;
    const char* Fw = Fs + pw * RP * FS;
    char* Hw = Hs + pw * RP * HS;
    int lr = lane & 15, lg = lane >> 4;

    f4v acc[MTW][NT];
#pragma unroll
    for (int m = 0; m < MTW; m++)
#pragma unroll
        for (int nt = 0; nt < NT; nt++)
#pragma unroll
            for (int q = 0; q < 4; q++) acc[m][nt][q] = 0.f;
#pragma unroll
    for (int ks = 0; ks < KS1; ks++) {
        s8v bfr[NT];
#pragma unroll
        for (int nt = 0; nt < NT; nt++)
            bfr[nt] = *(const s8v*)(Fw + (nt * 16 + lr) * FS + (32 * ks + lg * 8) * 2);
#pragma unroll
        for (int m = 0; m < MTW; m++) {
            s8v afr = *(const s8v*)(Wpa + (((size_t)(mt0 + m) * KS1 + ks) * 64 + lane) * 8);
#pragma unroll
            for (int nt = 0; nt < NT; nt++)
                acc[m][nt] = __builtin_amdgcn_mfma_f32_16x16x32_bf16(afr, bfr[nt], acc[m][nt], 0, 0, 0);
        }
    }
#pragma unroll
    for (int m = 0; m < MTW; m++) {
        int cbase = (mt0 + m) * 16 + lg * 4;
        f4v bv = *(const f4v*)(ba + cbase);
#pragma unroll
        for (int nt = 0; nt < NT; nt++) {
            s4v hq;
#pragma unroll
            for (int q = 0; q < 4; q++)
                hq[q] = bf16rne(fmaxf(acc[m][nt][q] + bv[q], 0.f));
            *(s4v*)(Hw + (nt * 16 + lr) * HS + cbase * 2) = hq;
        }
    }
    __syncthreads();

    f4v acc2[MTW][NT];
#pragma unroll
    for (int m = 0; m < MTW; m++)
#pragma unroll
        for (int nt = 0; nt < NT; nt++)
#pragma unroll
            for (int q = 0; q < 4; q++) acc2[m][nt][q] = 0.f;
#pragma unroll
    for (int ks = 0; ks < KS2; ks++) {
        s8v bfr[NT];
#pragma unroll
        for (int nt = 0; nt < NT; nt++)
            bfr[nt] = *(const s8v*)(Hw + (nt * 16 + lr) * HS + (32 * ks + lg * 8) * 2);
#pragma unroll
        for (int m = 0; m < MTW; m++) {
            s8v afr = *(const s8v*)(Wpb + (((size_t)(mt0 + m) * KS2 + ks) * 64 + lane) * 8);
#pragma unroll
            for (int nt = 0; nt < NT; nt++)
                acc2[m][nt] = __builtin_amdgcn_mfma_f32_16x16x32_bf16(afr, bfr[nt], acc2[m][nt], 0, 0, 0);
        }
    }

    const int* sjw = sj + pw * RP;
#pragma unroll
    for (int m = 0; m < MTW; m++) {
        int cbase = (mt0 + m) * 16 + lg * 4;
        f4v bv = *(const f4v*)(bb + cbase);
        f4v vmx;
#pragma unroll
        for (int q = 0; q < 4; q++) vmx[q] = 0.f;
#pragma unroll
        for (int nt = 0; nt < NT; nt++) {
            int s = nt * 16 + lr;
            bool valid = (s < 33) && (sjw[s] >= 0);
#pragma unroll
            for (int q = 0; q < 4; q++) {
                float v = fmaxf(acc2[m][nt][q] + bv[q], 0.f);
                if (valid) vmx[q] = fmaxf(vmx[q], v);
            }
        }
#pragma unroll
        for (int off = 1; off < 16; off <<= 1)
#pragma unroll
            for (int q = 0; q < 4; q++)
                vmx[q] = fmaxf(vmx[q], __shfl_xor(vmx[q], off, 64));
        if (lr == 0) {
            int pid = pid0 + pw;
            *(f4v*)(xout + (size_t)pid * CH + cbase) = vmx;
        }
    }
}

// ---------------------------------------------------------------------------
__global__ void gather_kernel(
        const float* __restrict__ pos_in, const float* __restrict__ x_in,
        const int* __restrict__ s, int Nin, int M, int C,
        float* __restrict__ pos_out, float* __restrict__ x_out) {
    int b = blockIdx.y, m = blockIdx.x, t = threadIdx.x;
    int j = s[b * M + m];
    x_out[((size_t)b * M + m) * C + t] = x_in[((size_t)b * Nin + j) * C + t];
    if (t < 3) pos_out[((size_t)b * M + m) * 3 + t] = pos_in[((size_t)b * Nin + j) * 3 + t];
}

// ---------------------------------------------------------------------------
// Global max pool + MLP head + log_softmax (unchanged).
// ---------------------------------------------------------------------------
__global__ __launch_bounds__(256) void head_kernel(
        const float* __restrict__ x3,
        const float* __restrict__ Wl1, const float* __restrict__ bl1,
        const float* __restrict__ Wl2, const float* __restrict__ bl2,
        const float* __restrict__ Wl3, const float* __restrict__ bl3,
        float* __restrict__ out) {
    __shared__ float gbuf[256], h1[256], h2[256], h3[40];
    int b = blockIdx.x, c = threadIdx.x;
    const float* xb = x3 + (size_t)b * 256 * 256;
    float m = -INFINITY;
    for (int r = 0; r < 256; r++) m = fmaxf(m, xb[r * 256 + c]);
    gbuf[c] = m;
    __syncthreads();
    float a = bl1[c];
    for (int k = 0; k < 256; k++) a = fmaf(gbuf[k], Wl1[k * 256 + c], a);
    h1[c] = fmaxf(a, 0.f);
    __syncthreads();
    a = bl2[c];
    for (int k = 0; k < 256; k++) a = fmaf(h1[k], Wl2[k * 256 + c], a);
    h2[c] = fmaxf(a, 0.f);
    __syncthreads();
    if (c < 40) {
        a = bl3[c];
        for (int k = 0; k < 256; k++) a = fmaf(h2[k], Wl3[k * 40 + c], a);
        h3[c] = a;
    }
    __syncthreads();
    if (c < 64) {
        float v = -INFINITY;
        if (c < 40) v = h3[c];
        float mx = v;
#pragma unroll
        for (int off = 32; off >= 1; off >>= 1) mx = fmaxf(mx, __shfl_xor(mx, off, 64));
        float e = (c < 40) ? expf(__fsub_rn(v, mx)) : 0.f;
        float s = e;
#pragma unroll
        for (int off = 32; off >= 1; off >>= 1) s = __fadd_rn(s, __shfl_xor(s, off, 64));
        float ls = logf(s);
        if (c < 40) out[b * 40 + c] = __fsub_rn(__fsub_rn(v, mx), ls);
    }
}

// ---------------------------------------------------------------------------
extern "C" void kernel_launch(void* const* d_in, const int* in_sizes, int n_in,
                              void* d_out, int out_size, void* d_ws, size_t ws_size,
                              hipStream_t stream) {
    (void)in_sizes; (void)n_in; (void)out_size; (void)ws_size;
    const float* pos = (const float*)d_in[0];
    const float* W1a = (const float*)d_in[2];
    const float* b1a = (const float*)d_in[3];
    const float* W1b = (const float*)d_in[4];
    const float* b1b = (const float*)d_in[5];
    const float* W2a = (const float*)d_in[6];
    const float* b2a = (const float*)d_in[7];
    const float* W2b = (const float*)d_in[8];
    const float* b2b = (const float*)d_in[9];
    const float* W3a = (const float*)d_in[10];
    const float* b3a = (const float*)d_in[11];
    const float* W3b = (const float*)d_in[12];
    const float* b3b = (const float*)d_in[13];
    const float* Wl1 = (const float*)d_in[14];
    const float* bl1 = (const float*)d_in[15];
    const float* Wl2 = (const float*)d_in[16];
    const float* bl2 = (const float*)d_in[17];
    const float* Wl3 = (const float*)d_in[18];
    const float* bl3 = (const float*)d_in[19];
    float* out = (float*)d_out;

    const int B = 32;
    char* w = (char*)d_ws;
    auto alloc = [&](size_t bytes) -> char* {
        char* r = w;
        w += (bytes + 255) & ~(size_t)255;
        return r;
    };
    int*   idx1 = (int*)  alloc((size_t)B * 2048 * 33 * 4);
    float* x1   = (float*)alloc((size_t)B * 2048 * 64 * 4);
    int*   s1   = (int*)  alloc((size_t)B * 1024 * 4);
    float* pos2 = (float*)alloc((size_t)B * 1024 * 3 * 4);
    float* x2in = (float*)alloc((size_t)B * 1024 * 64 * 4);
    int*   idx2 = (int*)  alloc((size_t)B * 1024 * 33 * 4);
    float* x2   = (float*)alloc((size_t)B * 1024 * 128 * 4);
    int*   s2   = (int*)  alloc((size_t)B * 256 * 4);
    float* pos3 = (float*)alloc((size_t)B * 256 * 3 * 4);
    float* x3in = (float*)alloc((size_t)B * 256 * 128 * 4);
    int*   idx3 = (int*)  alloc((size_t)B * 256 * 33 * 4);
    float* x3   = (float*)alloc((size_t)B * 256 * 256 * 4);
    short* Wp1a = (short*)alloc(4  * 1 * 64 * 8 * 2);
    short* Wp1b = (short*)alloc(4  * 2 * 64 * 8 * 2);
    short* Wp2a = (short*)alloc(8  * 3 * 64 * 8 * 2);
    short* Wp2b = (short*)alloc(8  * 4 * 64 * 8 * 2);
    short* Wp3a = (short*)alloc(16 * 5 * 64 * 8 * 2);
    short* Wp3b = (short*)alloc(16 * 8 * 64 * 8 * 2);

    pack_w_kernel<<<1,  256, 0, stream>>>(W1a, Wp1a, 3,   64,  1, 256);
    pack_w_kernel<<<2,  256, 0, stream>>>(W1b, Wp1b, 64,  64,  2, 512);
    pack_w_kernel<<<6,  256, 0, stream>>>(W2a, Wp2a, 67,  128, 3, 1536);
    pack_w_kernel<<<8,  256, 0, stream>>>(W2b, Wp2b, 128, 128, 4, 2048);
    pack_w_kernel<<<20, 256, 0, stream>>>(W3a, Wp3a, 131, 256, 5, 5120);
    pack_w_kernel<<<32, 256, 0, stream>>>(W3b, Wp3b, 256, 256, 8, 8192);

    // ---- SA module 1 (2048 pts, r=0.2): radius + FPS fused (independent) ----
    radius_fps_kernel<2048, 1024><<<dim3(B, 513), 256, 0, stream>>>(
        pos, 0.04f, idx1, s1);
    conv_mfma_kernel<0, 64, 4, 2048><<<B * 2048 / 4, 256, 0, stream>>>(
        pos, nullptr, idx1, Wp1a, b1a, Wp1b, b1b, x1);
    gather_kernel<<<dim3(1024, B), 64, 0, stream>>>(pos, x1, s1, 2048, 1024, 64, pos2, x2in);

    // ---- SA module 2 (1024 pts, r=0.4): radius + FPS fused ----
    radius_fps_kernel<1024, 256><<<dim3(B, 257), 256, 0, stream>>>(
        pos2, 0.16f, idx2, s2);
    conv_mfma_kernel<64, 128, 1, 1024><<<B * 1024, 256, 0, stream>>>(
        pos2, x2in, idx2, Wp2a, b2a, Wp2b, b2b, x2);
    gather_kernel<<<dim3(256, B), 128, 0, stream>>>(pos2, x2, s2, 1024, 256, 128, pos3, x3in);

    // ---- SA module 3 (256 pts, r=1.0) ----
    radius_topk_kernel<256><<<dim3(B, 64), 256, 0, stream>>>(pos3, 1.0f, idx3);
    conv_mfma_kernel<128, 256, 1, 256><<<B * 256, 256, 0, stream>>>(
        pos3, x3in, idx3, Wp3a, b3a, Wp3b, b3b, x3);

    // ---- global pool + head ----
    head_kernel<<<B, 256, 0, stream>>>(x3, Wl1, bl1, Wl2, bl2, Wl3, bl3, out);
}

// Round 9
// 2167.691 us; speedup vs baseline: 1.8224x; 1.0267x over previous
//
#include <hip/hip_runtime.h>
#include <math.h>

#define DEV static __device__ __forceinline__

typedef short s8v  __attribute__((ext_vector_type(8)));   // 8 bf16 (A/B frag)
typedef short s4v  __attribute__((ext_vector_type(4)));
typedef float f4v  __attribute__((ext_vector_type(4)));   // C/D frag

// round-to-nearest-even f32 -> bf16 (bits in a short)
DEV short bf16rne(float f) {
    unsigned u = __float_as_uint(f);
    unsigned r = (u + 0x7fffu + ((u >> 16) & 1u)) >> 16;
    return (short)r;
}

// Exact-IEEE squared distance, same op order as the numpy/XLA reference.
DEV float sqd(float ax, float ay, float az, float bx, float by, float bz) {
    float dx = __fsub_rn(ax, bx), dy = __fsub_rn(ay, by), dz = __fsub_rn(az, bz);
    return __fadd_rn(__fadd_rn(__fmul_rn(dx, dx), __fmul_rn(dy, dy)), __fmul_rn(dz, dz));
}

// ---------------------------------------------------------------------------
// DPP argmax step: combine own (key,coords) with DPP-shuffled partner's.
// VALU-pipe cross-lane (~4-8cyc) vs ds_bpermute (~120cyc) — the round-8
// post-mortem showed the u64 shfl_xor chain (2 dependent bpermutes x 6 steps)
// was ~1400cyc of the FPS iteration.  old=own value => rows excluded by
// ROWMASK no-op (cmp own>own = false).
// ---------------------------------------------------------------------------
template <int CTRL, int ROWMASK>
DEV void fps_dpp_step(unsigned long long& k, float& bx, float& by, float& bz) {
    unsigned klo = (unsigned)k, khi = (unsigned)(k >> 32);
    int olo = __builtin_amdgcn_update_dpp((int)klo, (int)klo, CTRL, ROWMASK, 0xF, false);
    int ohi = __builtin_amdgcn_update_dpp((int)khi, (int)khi, CTRL, ROWMASK, 0xF, false);
    int oxi = __builtin_amdgcn_update_dpp(__float_as_int(bx), __float_as_int(bx), CTRL, ROWMASK, 0xF, false);
    int oyi = __builtin_amdgcn_update_dpp(__float_as_int(by), __float_as_int(by), CTRL, ROWMASK, 0xF, false);
    int ozi = __builtin_amdgcn_update_dpp(__float_as_int(bz), __float_as_int(bz), CTRL, ROWMASK, 0xF, false);
    unsigned long long ok = (((unsigned long long)(unsigned)ohi) << 32) | (unsigned)olo;
    bool take = ok > k;
    k  = take ? ok : k;
    bx = take ? __int_as_float(oxi) : bx;
    by = take ? __int_as_float(oyi) : by;
    bz = take ? __int_as_float(ozi) : bz;
}

// Full-wave argmax of (key, coords); result valid in LANE 63.
// xor1, xor2, xor7(row_half_mirror), xor15(row_mirror) reduce each row of 16;
// row_bcast15 (rm 0xa) folds row r into r+1; row_bcast31 (rm 0xc) folds
// lanes 0-31 into rows 2,3 => lane 63 holds the full 64-lane reduction.
DEV void fps_wave_argmax(unsigned long long& k, float& bx, float& by, float& bz) {
    fps_dpp_step<0xB1,  0xF>(k, bx, by, bz);   // quad_perm [1,0,3,2]  (xor1)
    fps_dpp_step<0x4E,  0xF>(k, bx, by, bz);   // quad_perm [2,3,0,1]  (xor2)
    fps_dpp_step<0x141, 0xF>(k, bx, by, bz);   // row_half_mirror      (xor7)
    fps_dpp_step<0x140, 0xF>(k, bx, by, bz);   // row_mirror           (xor15)
    fps_dpp_step<0x142, 0xA>(k, bx, by, bz);   // row_bcast15 -> rows 1,3
    fps_dpp_step<0x143, 0xC>(k, bx, by, bz);   // row_bcast31 -> rows 2,3
}

// ---------------------------------------------------------------------------
// Fused radius top-k + FPS. blockIdx.y < N/4: radius (one wave/query).
// blockIdx.y == N/4: 256-thread FPS for the whole cloud.
// FPS: round-8 structure (serial fused scan, small live set; winners in LDS)
// with the ds_bpermute butterfly replaced by the DPP argmax above.
// Selection math exact-IEEE fp32; key=(d2_bits<<32)|~j => ties -> lowest j.
// ---------------------------------------------------------------------------
template <int N, int M>
__global__ __launch_bounds__(256) void radius_fps_kernel(
        const float* __restrict__ pos, float rr, int* __restrict__ idx_out,
        int* __restrict__ s_out) {
    __shared__ __align__(16) unsigned long long wkey[2][4];
    __shared__ __align__(16) float wxyz[2][4][4];
    __shared__ int swin[M];
    int b = blockIdx.x;
    const float* p = pos + (size_t)b * N * 3;

    if (blockIdx.y == N / 4) {
        // ---------------- FPS path: 256 threads, 1 barrier/iter ----------------
        constexpr int P = N / 256;
        int tid = threadIdx.x;
        int w = tid >> 6, lane = tid & 63;
        float cx[P], cy[P], cz[P], d[P];
#pragma unroll
        for (int q = 0; q < P; q++) {
            int j = q * 256 + tid;
            cx[q] = p[j * 3 + 0];
            cy[q] = p[j * 3 + 1];
            cz[q] = p[j * 3 + 2];
            d[q] = INFINITY;
        }
        float sx = p[0], sy = p[1], sz = p[2];
        if (tid == 0) swin[0] = 0;
#pragma unroll 1
        for (int m = 1; m < M; m++) {
            // fused d-update + serial argmax scan (small live set: 5 values)
            float best = -INFINITY, bx = 0.f, by = 0.f, bz = 0.f;
            int bj = 0;
#pragma unroll
            for (int q = 0; q < P; q++) {
                float di = sqd(cx[q], cy[q], cz[q], sx, sy, sz);
                float dn = fminf(d[q], di);
                d[q] = dn;
                bool take = dn > best;     // strict >, q asc => lowest j in lane
                best = take ? dn : best;
                bj = take ? (q * 256 + tid) : bj;
                bx = take ? cx[q] : bx;
                by = take ? cy[q] : by;
                bz = take ? cz[q] : bz;
            }
            unsigned long long key =
                (((unsigned long long)__float_as_uint(best)) << 32)
                | (unsigned)(0xFFFFFFFFu - (unsigned)bj);
            // DPP wave argmax: result (key+coords) valid in lane 63
            fps_wave_argmax(key, bx, by, bz);
            int par = m & 1;
            if (lane == 63) {
                wkey[par][w] = key;
                f4v cv; cv[0] = bx; cv[1] = by; cv[2] = bz; cv[3] = 0.f;
                *(f4v*)&wxyz[par][w][0] = cv;
            }
            __syncthreads();
            unsigned long long k0 = wkey[par][0], k1 = wkey[par][1];
            unsigned long long k2 = wkey[par][2], k3 = wkey[par][3];
            f4v c0 = *(const f4v*)&wxyz[par][0][0];
            f4v c1 = *(const f4v*)&wxyz[par][1][0];
            f4v c2 = *(const f4v*)&wxyz[par][2][0];
            f4v c3 = *(const f4v*)&wxyz[par][3][0];
            bool a01 = k1 > k0;
            unsigned long long k01 = a01 ? k1 : k0;
            f4v c01 = a01 ? c1 : c0;
            bool a23 = k3 > k2;
            unsigned long long k23 = a23 ? k3 : k2;
            f4v c23 = a23 ? c3 : c2;
            bool af = k23 > k01;
            unsigned long long kf = af ? k23 : k01;
            f4v cf = af ? c23 : c01;
            sx = cf[0]; sy = cf[1]; sz = cf[2];
            if (tid == 0)
                swin[m] = (int)(0xFFFFFFFFu - (unsigned)(kf & 0xFFFFFFFFull));
        }
        __syncthreads();
        int* so = s_out + b * M;
        for (int j = tid; j < M; j += 256) so[j] = swin[j];
        return;
    }

    // ---------------- radius top-k path: one wave per query (unchanged) ----
    constexpr int Q = N / 64;
    constexpr unsigned long long INV = ~0ull;
    int wid = threadIdx.x >> 6, lane = threadIdx.x & 63;
    int i = blockIdx.y * 4 + wid;
    float qx = p[i * 3 + 0], qy = p[i * 3 + 1], qz = p[i * 3 + 2];

    unsigned long long c[Q];
#pragma unroll
    for (int q = 0; q < Q; q++) {
        int jj = q * 64 + lane;
        float px = p[jj * 3 + 0], py = p[jj * 3 + 1], pz = p[jj * 3 + 2];
        float d2 = sqd(px, py, pz, qx, qy, qz);
        bool valid = (jj != i) && (d2 <= rr);
        c[q] = valid ? ((((unsigned long long)__float_as_uint(d2)) << 32)
                        | (unsigned)jj)
                     : INV;
    }

#pragma unroll
    for (int k = 2; k <= Q; k <<= 1) {
#pragma unroll
        for (int jj = k >> 1; jj > 0; jj >>= 1) {
#pragma unroll
            for (int t = 0; t < Q; t++) {
                int l = t ^ jj;
                if (l > t) {
                    bool up = ((t & k) == 0);
                    unsigned long long a = c[t], d = c[l];
                    bool sw = (a > d) != up;
                    c[t] = sw ? d : a;
                    c[l] = sw ? a : d;
                }
            }
        }
    }

    int* orow = idx_out + ((size_t)b * N + i) * 33;
    int cnt = 0;
    for (int s = 0; s < 32; s++) {
        unsigned long long h = c[0];
        unsigned long long g = h;
#pragma unroll
        for (int off = 1; off < 64; off <<= 1) {
            unsigned long long o = __shfl_xor(g, off, 64);
            g = (o < g) ? o : g;
        }
        if (lane == 0) orow[s] = (int)(unsigned)(g & 0xffffffffull);
        cnt += (g != INV) ? 1 : 0;
        if (h == g && g != INV) {
#pragma unroll
            for (int q = 0; q < Q - 1; q++) c[q] = c[q + 1];
            c[Q - 1] = INV;
        }
    }
    if (lane == 0) {
        if (cnt < 32) orow[cnt] = i;
        orow[32] = (cnt == 32) ? i : -1;
    }
}

// ---------------------------------------------------------------------------
// Plain radius top-k (stage 3, no FPS needed). Unchanged.
// ---------------------------------------------------------------------------
template <int N>
__global__ __launch_bounds__(256) void radius_topk_kernel(
        const float* __restrict__ pos, float rr, int* __restrict__ idx_out) {
    constexpr int Q = N / 64;
    constexpr unsigned long long INV = ~0ull;
    int b = blockIdx.x;
    int wid = threadIdx.x >> 6, lane = threadIdx.x & 63;
    int i = blockIdx.y * 4 + wid;
    const float* p = pos + (size_t)b * N * 3;
    float qx = p[i * 3 + 0], qy = p[i * 3 + 1], qz = p[i * 3 + 2];

    unsigned long long c[Q];
#pragma unroll
    for (int q = 0; q < Q; q++) {
        int jj = q * 64 + lane;
        float px = p[jj * 3 + 0], py = p[jj * 3 + 1], pz = p[jj * 3 + 2];
        float d2 = sqd(px, py, pz, qx, qy, qz);
        bool valid = (jj != i) && (d2 <= rr);
        c[q] = valid ? ((((unsigned long long)__float_as_uint(d2)) << 32)
                        | (unsigned)jj)
                     : INV;
    }

#pragma unroll
    for (int k = 2; k <= Q; k <<= 1) {
#pragma unroll
        for (int jj = k >> 1; jj > 0; jj >>= 1) {
#pragma unroll
            for (int t = 0; t < Q; t++) {
                int l = t ^ jj;
                if (l > t) {
                    bool up = ((t & k) == 0);
                    unsigned long long a = c[t], d = c[l];
                    bool sw = (a > d) != up;
                    c[t] = sw ? d : a;
                    c[l] = sw ? a : d;
                }
            }
        }
    }

    int* orow = idx_out + ((size_t)b * N + i) * 33;
    int cnt = 0;
    for (int s = 0; s < 32; s++) {
        unsigned long long h = c[0];
        unsigned long long g = h;
#pragma unroll
        for (int off = 1; off < 64; off <<= 1) {
            unsigned long long o = __shfl_xor(g, off, 64);
            g = (o < g) ? o : g;
        }
        if (lane == 0) orow[s] = (int)(unsigned)(g & 0xffffffffull);
        cnt += (g != INV) ? 1 : 0;
        if (h == g && g != INV) {
#pragma unroll
            for (int q = 0; q < Q - 1; q++) c[q] = c[q + 1];
            c[Q - 1] = INV;
        }
    }
    if (lane == 0) {
        if (cnt < 32) orow[cnt] = i;
        orow[32] = (cnt == 32) ? i : -1;
    }
}

// ---------------------------------------------------------------------------
// Weight pre-pack (unchanged).
// ---------------------------------------------------------------------------
__global__ void pack_w_kernel(const float* __restrict__ W, short* __restrict__ out,
                              int Kreal, int C, int KS, int total) {
    int t = blockIdx.x * 256 + threadIdx.x;
    if (t >= total) return;
    int lane = t & 63;
    int mk = t >> 6;
    int ks = mk % KS, mt = mk / KS;
    int c = 16 * mt + (lane & 15);
    int k0 = 32 * ks + ((lane >> 4) << 3);
    s8v v;
#pragma unroll
    for (int j = 0; j < 8; j++) {
        int k = k0 + j;
        v[j] = (k < Kreal) ? bf16rne(W[(size_t)k * C + c]) : (short)0;
    }
    *(s8v*)(out + (size_t)t * 8) = v;
}

// ---------------------------------------------------------------------------
// Fused MFMA point-conv (unchanged).
// ---------------------------------------------------------------------------
template <int CXIN, int CH, int PPB, int N>
__global__ __launch_bounds__(256) void conv_mfma_kernel(
        const float* __restrict__ pos, const float* __restrict__ xin,
        const int* __restrict__ idx,
        const short* __restrict__ Wpa, const float* __restrict__ ba,
        const short* __restrict__ Wpb, const float* __restrict__ bb,
        float* __restrict__ xout) {
    constexpr int CIN  = CXIN + 3;
    constexpr int CINp = (CIN + 31) & ~31;
    constexpr int KS1  = CINp / 32, KS2 = CH / 32;
    constexpr int MT   = CH / 16;
    constexpr int MTW  = (PPB == 4) ? MT : MT / 4;
    constexpr int RP   = 48;
    constexpr int NT   = 3;
    constexpr int FS   = CINp * 2 + 16;
    constexpr int HS   = CH * 2 + 16;
    __shared__ __align__(16) char Fs[PPB * RP * FS];
    __shared__ __align__(16) char Hs[PPB * RP * HS];
    __shared__ int sj[PPB * RP];

    int tid = threadIdx.x;
    int lane = tid & 63, wid = tid >> 6;
    int pid0 = blockIdx.x * PPB;

    for (int r = tid; r < PPB * RP; r += 256) {
        int p = r / RP, s = r - p * RP;
        sj[r] = (s < 33) ? idx[(size_t)(pid0 + p) * 33 + s] : -1;
    }
    __syncthreads();

    constexpr int FE = PPB * RP * CINp;
    for (int e = tid; e < FE; e += 256) {
        int r = e / CINp, f = e - r * CINp;
        int p = r / RP;
        int pid = pid0 + p;
        int b = pid / N, i = pid - b * N;
        int j = sj[r];
        float v = 0.f;
        if (j >= 0 && f < CIN) {
            if (f < CXIN) {
                v = xin[((size_t)b * N + j) * CXIN + f];
            } else {
                int a = f - CXIN;
                v = __fsub_rn(pos[((size_t)b * N + j) * 3 + a],
                              pos[((size_t)b * N + i) * 3 + a]);
            }
        }
        *(short*)(Fs + (size_t)r * FS + f * 2) = bf16rne(v);
    }
    __syncthreads();

    int pw  = (PPB == 4) ? wid : 0;
    int mt0 = (PPB == 4) ? 0 : wid * MTW;
    const char* Fw = Fs + pw * RP * FS;
    char* Hw = Hs + pw * RP * HS;
    int lr = lane & 15, lg = lane >> 4;

    f4v acc[MTW][NT];
#pragma unroll
    for (int m = 0; m < MTW; m++)
#pragma unroll
        for (int nt = 0; nt < NT; nt++)
#pragma unroll
            for (int q = 0; q < 4; q++) acc[m][nt][q] = 0.f;
#pragma unroll
    for (int ks = 0; ks < KS1; ks++) {
        s8v bfr[NT];
#pragma unroll
        for (int nt = 0; nt < NT; nt++)
            bfr[nt] = *(const s8v*)(Fw + (nt * 16 + lr) * FS + (32 * ks + lg * 8) * 2);
#pragma unroll
        for (int m = 0; m < MTW; m++) {
            s8v afr = *(const s8v*)(Wpa + (((size_t)(mt0 + m) * KS1 + ks) * 64 + lane) * 8);
#pragma unroll
            for (int nt = 0; nt < NT; nt++)
                acc[m][nt] = __builtin_amdgcn_mfma_f32_16x16x32_bf16(afr, bfr[nt], acc[m][nt], 0, 0, 0);
        }
    }
#pragma unroll
    for (int m = 0; m < MTW; m++) {
        int cbase = (mt0 + m) * 16 + lg * 4;
        f4v bv = *(const f4v*)(ba + cbase);
#pragma unroll
        for (int nt = 0; nt < NT; nt++) {
            s4v hq;
#pragma unroll
            for (int q = 0; q < 4; q++)
                hq[q] = bf16rne(fmaxf(acc[m][nt][q] + bv[q], 0.f));
            *(s4v*)(Hw + (nt * 16 + lr) * HS + cbase * 2) = hq;
        }
    }
    __syncthreads();

    f4v acc2[MTW][NT];
#pragma unroll
    for (int m = 0; m < MTW; m++)
#pragma unroll
        for (int nt = 0; nt < NT; nt++)
#pragma unroll
            for (int q = 0; q < 4; q++) acc2[m][nt][q] = 0.f;
#pragma unroll
    for (int ks = 0; ks < KS2; ks++) {
        s8v bfr[NT];
#pragma unroll
        for (int nt = 0; nt < NT; nt++)
            bfr[nt] = *(const s8v*)(Hw + (nt * 16 + lr) * HS + (32 * ks + lg * 8) * 2);
#pragma unroll
        for (int m = 0; m < MTW; m++) {
            s8v afr = *(const s8v*)(Wpb + (((size_t)(mt0 + m) * KS2 + ks) * 64 + lane) * 8);
#pragma unroll
            for (int nt = 0; nt < NT; nt++)
                acc2[m][nt] = __builtin_amdgcn_mfma_f32_16x16x32_bf16(afr, bfr[nt], acc2[m][nt], 0, 0, 0);
        }
    }

    const int* sjw = sj + pw * RP;
#pragma unroll
    for (int m = 0; m < MTW; m++) {
        int cbase = (mt0 + m) * 16 + lg * 4;
        f4v bv = *(const f4v*)(bb + cbase);
        f4v vmx;
#pragma unroll
        for (int q = 0; q < 4; q++) vmx[q] = 0.f;
#pragma unroll
        for (int nt = 0; nt < NT; nt++) {
            int s = nt * 16 + lr;
            bool valid = (s < 33) && (sjw[s] >= 0);
#pragma unroll
            for (int q = 0; q < 4; q++) {
                float v = fmaxf(acc2[m][nt][q] + bv[q], 0.f);
                if (valid) vmx[q] = fmaxf(vmx[q], v);
            }
        }
#pragma unroll
        for (int off = 1; off < 16; off <<= 1)
#pragma unroll
            for (int q = 0; q < 4; q++)
                vmx[q] = fmaxf(vmx[q], __shfl_xor(vmx[q], off, 64));
        if (lr == 0) {
            int pid = pid0 + pw;
            *(f4v*)(xout + (size_t)pid * CH + cbase) = vmx;
        }
    }
}

// ---------------------------------------------------------------------------
__global__ void gather_kernel(
        const float* __restrict__ pos_in, const float* __restrict__ x_in,
        const int* __restrict__ s, int Nin, int M, int C,
        float* __restrict__ pos_out, float* __restrict__ x_out) {
    int b = blockIdx.y, m = blockIdx.x, t = threadIdx.x;
    int j = s[b * M + m];
    x_out[((size_t)b * M + m) * C + t] = x_in[((size_t)b * Nin + j) * C + t];
    if (t < 3) pos_out[((size_t)b * M + m) * 3 + t] = pos_in[((size_t)b * Nin + j) * 3 + t];
}

// ---------------------------------------------------------------------------
// Global max pool + MLP head + log_softmax (unchanged).
// ---------------------------------------------------------------------------
__global__ __launch_bounds__(256) void head_kernel(
        const float* __restrict__ x3,
        const float* __restrict__ Wl1, const float* __restrict__ bl1,
        const float* __restrict__ Wl2, const float* __restrict__ bl2,
        const float* __restrict__ Wl3, const float* __restrict__ bl3,
        float* __restrict__ out) {
    __shared__ float gbuf[256], h1[256], h2[256], h3[40];
    int b = blockIdx.x, c = threadIdx.x;
    const float* xb = x3 + (size_t)b * 256 * 256;
    float m = -INFINITY;
    for (int r = 0; r < 256; r++) m = fmaxf(m, xb[r * 256 + c]);
    gbuf[c] = m;
    __syncthreads();
    float a = bl1[c];
    for (int k = 0; k < 256; k++) a = fmaf(gbuf[k], Wl1[k * 256 + c], a);
    h1[c] = fmaxf(a, 0.f);
    __syncthreads();
    a = bl2[c];
    for (int k = 0; k < 256; k++) a = fmaf(h1[k], Wl2[k * 256 + c], a);
    h2[c] = fmaxf(a, 0.f);
    __syncthreads();
    if (c < 40) {
        a = bl3[c];
        for (int k = 0; k < 256; k++) a = fmaf(h2[k], Wl3[k * 40 + c], a);
        h3[c] = a;
    }
    __syncthreads();
    if (c < 64) {
        float v = -INFINITY;
        if (c < 40) v = h3[c];
        float mx = v;
#pragma unroll
        for (int off = 32; off >= 1; off >>= 1) mx = fmaxf(mx, __shfl_xor(mx, off, 64));
        float e = (c < 40) ? expf(__fsub_rn(v, mx)) : 0.f;
        float s = e;
#pragma unroll
        for (int off = 32; off >= 1; off >>= 1) s = __fadd_rn(s, __shfl_xor(s, off, 64));
        float ls = logf(s);
        if (c < 40) out[b * 40 + c] = __fsub_rn(__fsub_rn(v, mx), ls);
    }
}

// ---------------------------------------------------------------------------
extern "C" void kernel_launch(void* const* d_in, const int* in_sizes, int n_in,
                              void* d_out, int out_size, void* d_ws, size_t ws_size,
                              hipStream_t stream) {
    (void)in_sizes; (void)n_in; (void)out_size; (void)ws_size;
    const float* pos = (const float*)d_in[0];
    const float* W1a = (const float*)d_in[2];
    const float* b1a = (const float*)d_in[3];
    const float* W1b = (const float*)d_in[4];
    const float* b1b = (const float*)d_in[5];
    const float* W2a = (const float*)d_in[6];
    const float* b2a = (const float*)d_in[7];
    const float* W2b = (const float*)d_in[8];
    const float* b2b = (const float*)d_in[9];
    const float* W3a = (const float*)d_in[10];
    const float* b3a = (const float*)d_in[11];
    const float* W3b = (const float*)d_in[12];
    const float* b3b = (const float*)d_in[13];
    const float* Wl1 = (const float*)d_in[14];
    const float* bl1 = (const float*)d_in[15];
    const float* Wl2 = (const float*)d_in[16];
    const float* bl2 = (const float*)d_in[17];
    const float* Wl3 = (const float*)d_in[18];
    const float* bl3 = (const float*)d_in[19];
    float* out = (float*)d_out;

    const int B = 32;
    char* w = (char*)d_ws;
    auto alloc = [&](size_t bytes) -> char* {
        char* r = w;
        w += (bytes + 255) & ~(size_t)255;
        return r;
    };
    int*   idx1 = (int*)  alloc((size_t)B * 2048 * 33 * 4);
    float* x1   = (float*)alloc((size_t)B * 2048 * 64 * 4);
    int*   s1   = (int*)  alloc((size_t)B * 1024 * 4);
    float* pos2 = (float*)alloc((size_t)B * 1024 * 3 * 4);
    float* x2in = (float*)alloc((size_t)B * 1024 * 64 * 4);
    int*   idx2 = (int*)  alloc((size_t)B * 1024 * 33 * 4);
    float* x2   = (float*)alloc((size_t)B * 1024 * 128 * 4);
    int*   s2   = (int*)  alloc((size_t)B * 256 * 4);
    float* pos3 = (float*)alloc((size_t)B * 256 * 3 * 4);
    float* x3in = (float*)alloc((size_t)B * 256 * 128 * 4);
    int*   idx3 = (int*)  alloc((size_t)B * 256 * 33 * 4);
    float* x3   = (float*)alloc((size_t)B * 256 * 256 * 4);
    short* Wp1a = (short*)alloc(4  * 1 * 64 * 8 * 2);
    short* Wp1b = (short*)alloc(4  * 2 * 64 * 8 * 2);
    short* Wp2a = (short*)alloc(8  * 3 * 64 * 8 * 2);
    short* Wp2b = (short*)alloc(8  * 4 * 64 * 8 * 2);
    short* Wp3a = (short*)alloc(16 * 5 * 64 * 8 * 2);
    short* Wp3b = (short*)alloc(16 * 8 * 64 * 8 * 2);

    pack_w_kernel<<<1,  256, 0, stream>>>(W1a, Wp1a, 3,   64,  1, 256);
    pack_w_kernel<<<2,  256, 0, stream>>>(W1b, Wp1b, 64,  64,  2, 512);
    pack_w_kernel<<<6,  256, 0, stream>>>(W2a, Wp2a, 67,  128, 3, 1536);
    pack_w_kernel<<<8,  256, 0, stream>>>(W2b, Wp2b, 128, 128, 4, 2048);
    pack_w_kernel<<<20, 256, 0, stream>>>(W3a, Wp3a, 131, 256, 5, 5120);
    pack_w_kernel<<<32, 256, 0, stream>>>(W3b, Wp3b, 256, 256, 8, 8192);

    // ---- SA module 1 (2048 pts, r=0.2): radius + FPS fused (independent) ----
    radius_fps_kernel<2048, 1024><<<dim3(B, 513), 256, 0, stream>>>(
        pos, 0.04f, idx1, s1);
    conv_mfma_kernel<0, 64, 4, 2048><<<B * 2048 / 4, 256, 0, stream>>>(
        pos, nullptr, idx1, Wp1a, b1a, Wp1b, b1b, x1);
    gather_kernel<<<dim3(1024, B), 64, 0, stream>>>(pos, x1, s1, 2048, 1024, 64, pos2, x2in);

    // ---- SA module 2 (1024 pts, r=0.4): radius + FPS fused ----
    radius_fps_kernel<1024, 256><<<dim3(B, 257), 256, 0, stream>>>(
        pos2, 0.16f, idx2, s2);
    conv_mfma_kernel<64, 128, 1, 1024><<<B * 1024, 256, 0, stream>>>(
        pos2, x2in, idx2, Wp2a, b2a, Wp2b, b2b, x2);
    gather_kernel<<<dim3(256, B), 128, 0, stream>>>(pos2, x2, s2, 1024, 256, 128, pos3, x3in);

    // ---- SA module 3 (256 pts, r=1.0) ----
    radius_topk_kernel<256><<<dim3(B, 64), 256, 0, stream>>>(pos3, 1.0f, idx3);
    conv_mfma_kernel<128, 256, 1, 256><<<B * 256, 256, 0, stream>>>(
        pos3, x3in, idx3, Wp3a, b3a, Wp3b, b3b, x3);

    // ---- global pool + head ----
    head_kernel<<<B, 256, 0, stream>>>(x3, Wl1, bl1, Wl2, bl2, Wl3, bl3, out);
}

// Round 10
// 2114.135 us; speedup vs baseline: 1.8686x; 1.0253x over previous
//
#include <hip/hip_runtime.h>
#include <math.h>

#define DEV static __device__ __forceinline__

typedef short s8v  __attribute__((ext_vector_type(8)));   // 8 bf16 (A/B frag)
typedef short s4v  __attribute__((ext_vector_type(4)));
typedef float f4v  __attribute__((ext_vector_type(4)));   // C/D frag

// round-to-nearest-even f32 -> bf16 (bits in a short)
DEV short bf16rne(float f) {
    unsigned u = __float_as_uint(f);
    unsigned r = (u + 0x7fffu + ((u >> 16) & 1u)) >> 16;
    return (short)r;
}

// Exact-IEEE squared distance, same op order as the numpy/XLA reference.
DEV float sqd(float ax, float ay, float az, float bx, float by, float bz) {
    float dx = __fsub_rn(ax, bx), dy = __fsub_rn(ay, by), dz = __fsub_rn(az, bz);
    return __fadd_rn(__fadd_rn(__fmul_rn(dx, dx), __fmul_rn(dy, dy)), __fmul_rn(dz, dz));
}

// ---------------------------------------------------------------------------
// DPP u64 MIN step (radius extraction): VALU-pipe cross-lane (~4-8cyc) vs
// ds_bpermute (~120cyc). Round-9 evidence: the 32-round x 6-step bpermute
// chain (~23k cyc latency/wave) is the radius half's critical path.
// ---------------------------------------------------------------------------
template <int CTRL, int ROWMASK>
DEV void dpp_min_step(unsigned long long& k) {
    unsigned klo = (unsigned)k, khi = (unsigned)(k >> 32);
    int olo = __builtin_amdgcn_update_dpp((int)klo, (int)klo, CTRL, ROWMASK, 0xF, false);
    int ohi = __builtin_amdgcn_update_dpp((int)khi, (int)khi, CTRL, ROWMASK, 0xF, false);
    unsigned long long ok = (((unsigned long long)(unsigned)ohi) << 32) | (unsigned)olo;
    k = (ok < k) ? ok : k;
}

// Full-wave u64 min; result valid in lane 63, then broadcast via readlane.
DEV unsigned long long dpp_wave_min_bcast(unsigned long long k) {
    dpp_min_step<0xB1,  0xF>(k);   // quad_perm [1,0,3,2]  (xor1)
    dpp_min_step<0x4E,  0xF>(k);   // quad_perm [2,3,0,1]  (xor2)
    dpp_min_step<0x141, 0xF>(k);   // row_half_mirror      (xor7)
    dpp_min_step<0x140, 0xF>(k);   // row_mirror           (xor15)
    dpp_min_step<0x142, 0xA>(k);   // row_bcast15 -> rows 1,3
    dpp_min_step<0x143, 0xC>(k);   // row_bcast31 -> rows 2,3 (lane63 = wave min)
    unsigned glo = (unsigned)__builtin_amdgcn_readlane((int)(unsigned)k, 63);
    unsigned ghi = (unsigned)__builtin_amdgcn_readlane((int)(unsigned)(k >> 32), 63);
    return (((unsigned long long)ghi) << 32) | glo;   // uniform (SGPR)
}

// ---------------------------------------------------------------------------
// DPP argmax step for FPS (key + coords carried), from round 9.
// ---------------------------------------------------------------------------
template <int CTRL, int ROWMASK>
DEV void fps_dpp_step(unsigned long long& k, float& bx, float& by, float& bz) {
    unsigned klo = (unsigned)k, khi = (unsigned)(k >> 32);
    int olo = __builtin_amdgcn_update_dpp((int)klo, (int)klo, CTRL, ROWMASK, 0xF, false);
    int ohi = __builtin_amdgcn_update_dpp((int)khi, (int)khi, CTRL, ROWMASK, 0xF, false);
    int oxi = __builtin_amdgcn_update_dpp(__float_as_int(bx), __float_as_int(bx), CTRL, ROWMASK, 0xF, false);
    int oyi = __builtin_amdgcn_update_dpp(__float_as_int(by), __float_as_int(by), CTRL, ROWMASK, 0xF, false);
    int ozi = __builtin_amdgcn_update_dpp(__float_as_int(bz), __float_as_int(bz), CTRL, ROWMASK, 0xF, false);
    unsigned long long ok = (((unsigned long long)(unsigned)ohi) << 32) | (unsigned)olo;
    bool take = ok > k;
    k  = take ? ok : k;
    bx = take ? __int_as_float(oxi) : bx;
    by = take ? __int_as_float(oyi) : by;
    bz = take ? __int_as_float(ozi) : bz;
}

DEV void fps_wave_argmax(unsigned long long& k, float& bx, float& by, float& bz) {
    fps_dpp_step<0xB1,  0xF>(k, bx, by, bz);
    fps_dpp_step<0x4E,  0xF>(k, bx, by, bz);
    fps_dpp_step<0x141, 0xF>(k, bx, by, bz);
    fps_dpp_step<0x140, 0xF>(k, bx, by, bz);
    fps_dpp_step<0x142, 0xA>(k, bx, by, bz);
    fps_dpp_step<0x143, 0xC>(k, bx, by, bz);
}

// ---------------------------------------------------------------------------
// Fused radius top-k + FPS. blockIdx.y < N/4: radius (one wave/query).
// blockIdx.y == N/4: 256-thread FPS for the whole cloud.
// Selection math exact-IEEE fp32; keys unique => ties resolve to lower j,
// matching lax.top_k / jnp.argmax semantics exactly.
// ---------------------------------------------------------------------------
template <int N, int M>
__global__ __launch_bounds__(256) void radius_fps_kernel(
        const float* __restrict__ pos, float rr, int* __restrict__ idx_out,
        int* __restrict__ s_out) {
    __shared__ __align__(16) unsigned long long wkey[2][4];
    __shared__ __align__(16) float wxyz[2][4][4];
    __shared__ int swin[M];
    int b = blockIdx.x;
    const float* p = pos + (size_t)b * N * 3;

    if (blockIdx.y == N / 4) {
        // ---------------- FPS path (round-9 structure, unchanged) ----------
        constexpr int P = N / 256;
        int tid = threadIdx.x;
        int w = tid >> 6, lane = tid & 63;
        float cx[P], cy[P], cz[P], d[P];
#pragma unroll
        for (int q = 0; q < P; q++) {
            int j = q * 256 + tid;
            cx[q] = p[j * 3 + 0];
            cy[q] = p[j * 3 + 1];
            cz[q] = p[j * 3 + 2];
            d[q] = INFINITY;
        }
        float sx = p[0], sy = p[1], sz = p[2];
        if (tid == 0) swin[0] = 0;
#pragma unroll 1
        for (int m = 1; m < M; m++) {
            float best = -INFINITY, bx = 0.f, by = 0.f, bz = 0.f;
            int bj = 0;
#pragma unroll
            for (int q = 0; q < P; q++) {
                float di = sqd(cx[q], cy[q], cz[q], sx, sy, sz);
                float dn = fminf(d[q], di);
                d[q] = dn;
                bool take = dn > best;     // strict >, q asc => lowest j in lane
                best = take ? dn : best;
                bj = take ? (q * 256 + tid) : bj;
                bx = take ? cx[q] : bx;
                by = take ? cy[q] : by;
                bz = take ? cz[q] : bz;
            }
            unsigned long long key =
                (((unsigned long long)__float_as_uint(best)) << 32)
                | (unsigned)(0xFFFFFFFFu - (unsigned)bj);
            fps_wave_argmax(key, bx, by, bz);
            int par = m & 1;
            if (lane == 63) {
                wkey[par][w] = key;
                f4v cv; cv[0] = bx; cv[1] = by; cv[2] = bz; cv[3] = 0.f;
                *(f4v*)&wxyz[par][w][0] = cv;
            }
            __syncthreads();
            unsigned long long k0 = wkey[par][0], k1 = wkey[par][1];
            unsigned long long k2 = wkey[par][2], k3 = wkey[par][3];
            f4v c0 = *(const f4v*)&wxyz[par][0][0];
            f4v c1 = *(const f4v*)&wxyz[par][1][0];
            f4v c2 = *(const f4v*)&wxyz[par][2][0];
            f4v c3 = *(const f4v*)&wxyz[par][3][0];
            bool a01 = k1 > k0;
            unsigned long long k01 = a01 ? k1 : k0;
            f4v c01 = a01 ? c1 : c0;
            bool a23 = k3 > k2;
            unsigned long long k23 = a23 ? k3 : k2;
            f4v c23 = a23 ? c3 : c2;
            bool af = k23 > k01;
            unsigned long long kf = af ? k23 : k01;
            f4v cf = af ? c23 : c01;
            sx = cf[0]; sy = cf[1]; sz = cf[2];
            if (tid == 0)
                swin[m] = (int)(0xFFFFFFFFu - (unsigned)(kf & 0xFFFFFFFFull));
        }
        __syncthreads();
        int* so = s_out + b * M;
        for (int j = tid; j < M; j += 256) so[j] = swin[j];
        return;
    }

    // ---------------- radius top-k path: one wave per query ----------------
    constexpr int Q = N / 64;
    constexpr unsigned long long INV = ~0ull;
    int wid = threadIdx.x >> 6, lane = threadIdx.x & 63;
    int i = blockIdx.y * 4 + wid;
    float qx = p[i * 3 + 0], qy = p[i * 3 + 1], qz = p[i * 3 + 2];

    unsigned long long c[Q];
#pragma unroll
    for (int q = 0; q < Q; q++) {
        int jj = q * 64 + lane;
        float px = p[jj * 3 + 0], py = p[jj * 3 + 1], pz = p[jj * 3 + 2];
        float d2 = sqd(px, py, pz, qx, qy, qz);
        bool valid = (jj != i) && (d2 <= rr);
        c[q] = valid ? ((((unsigned long long)__float_as_uint(d2)) << 32)
                        | (unsigned)jj)
                     : INV;
    }

#pragma unroll
    for (int k = 2; k <= Q; k <<= 1) {
#pragma unroll
        for (int jj = k >> 1; jj > 0; jj >>= 1) {
#pragma unroll
            for (int t = 0; t < Q; t++) {
                int l = t ^ jj;
                if (l > t) {
                    bool up = ((t & k) == 0);
                    unsigned long long a = c[t], d = c[l];
                    bool sw = (a > d) != up;
                    c[t] = sw ? d : a;
                    c[l] = sw ? a : d;
                }
            }
        }
    }

    int* orow = idx_out + ((size_t)b * N + i) * 33;
    int cnt = 0;
    for (int s = 0; s < 32; s++) {
        unsigned long long h = c[0];
        unsigned long long g = dpp_wave_min_bcast(h);   // uniform wave min
        if (lane == 0) orow[s] = (int)(unsigned)(g & 0xffffffffull);
        cnt += (g != INV) ? 1 : 0;
        if (h == g && g != INV) {   // unique winner pops its sorted head
#pragma unroll
            for (int q = 0; q < Q - 1; q++) c[q] = c[q + 1];
            c[Q - 1] = INV;
        }
    }
    if (lane == 0) {
        if (cnt < 32) orow[cnt] = i;
        orow[32] = (cnt == 32) ? i : -1;
    }
}

// ---------------------------------------------------------------------------
// Plain radius top-k (stage 3). Same DPP-min extraction.
// ---------------------------------------------------------------------------
template <int N>
__global__ __launch_bounds__(256) void radius_topk_kernel(
        const float* __restrict__ pos, float rr, int* __restrict__ idx_out) {
    constexpr int Q = N / 64;
    constexpr unsigned long long INV = ~0ull;
    int b = blockIdx.x;
    int wid = threadIdx.x >> 6, lane = threadIdx.x & 63;
    int i = blockIdx.y * 4 + wid;
    const float* p = pos + (size_t)b * N * 3;
    float qx = p[i * 3 + 0], qy = p[i * 3 + 1], qz = p[i * 3 + 2];

    unsigned long long c[Q];
#pragma unroll
    for (int q = 0; q < Q; q++) {
        int jj = q * 64 + lane;
        float px = p[jj * 3 + 0], py = p[jj * 3 + 1], pz = p[jj * 3 + 2];
        float d2 = sqd(px, py, pz, qx, qy, qz);
        bool valid = (jj != i) && (d2 <= rr);
        c[q] = valid ? ((((unsigned long long)__float_as_uint(d2)) << 32)
                        | (unsigned)jj)
                     : INV;
    }

#pragma unroll
    for (int k = 2; k <= Q; k <<= 1) {
#pragma unroll
        for (int jj = k >> 1; jj > 0; jj >>= 1) {
#pragma unroll
            for (int t = 0; t < Q; t++) {
                int l = t ^ jj;
                if (l > t) {
                    bool up = ((t & k) == 0);
                    unsigned long long a = c[t], d = c[l];
                    bool sw = (a > d) != up;
                    c[t] = sw ? d : a;
                    c[l] = sw ? a : d;
                }
            }
        }
    }

    int* orow = idx_out + ((size_t)b * N + i) * 33;
    int cnt = 0;
    for (int s = 0; s < 32; s++) {
        unsigned long long h = c[0];
        unsigned long long g = dpp_wave_min_bcast(h);
        if (lane == 0) orow[s] = (int)(unsigned)(g & 0xffffffffull);
        cnt += (g != INV) ? 1 : 0;
        if (h == g && g != INV) {
#pragma unroll
            for (int q = 0; q < Q - 1; q++) c[q] = c[q + 1];
            c[Q - 1] = INV;
        }
    }
    if (lane == 0) {
        if (cnt < 32) orow[cnt] = i;
        orow[32] = (cnt == 32) ? i : -1;
    }
}

// ---------------------------------------------------------------------------
// Weight pre-pack (unchanged).
// ---------------------------------------------------------------------------
__global__ void pack_w_kernel(const float* __restrict__ W, short* __restrict__ out,
                              int Kreal, int C, int KS, int total) {
    int t = blockIdx.x * 256 + threadIdx.x;
    if (t >= total) return;
    int lane = t & 63;
    int mk = t >> 6;
    int ks = mk % KS, mt = mk / KS;
    int c = 16 * mt + (lane & 15);
    int k0 = 32 * ks + ((lane >> 4) << 3);
    s8v v;
#pragma unroll
    for (int j = 0; j < 8; j++) {
        int k = k0 + j;
        v[j] = (k < Kreal) ? bf16rne(W[(size_t)k * C + c]) : (short)0;
    }
    *(s8v*)(out + (size_t)t * 8) = v;
}

// ---------------------------------------------------------------------------
// Fused MFMA point-conv (unchanged).
// ---------------------------------------------------------------------------
template <int CXIN, int CH, int PPB, int N>
__global__ __launch_bounds__(256) void conv_mfma_kernel(
        const float* __restrict__ pos, const float* __restrict__ xin,
        const int* __restrict__ idx,
        const short* __restrict__ Wpa, const float* __restrict__ ba,
        const short* __restrict__ Wpb, const float* __restrict__ bb,
        float* __restrict__ xout) {
    constexpr int CIN  = CXIN + 3;
    constexpr int CINp = (CIN + 31) & ~31;
    constexpr int KS1  = CINp / 32, KS2 = CH / 32;
    constexpr int MT   = CH / 16;
    constexpr int MTW  = (PPB == 4) ? MT : MT / 4;
    constexpr int RP   = 48;
    constexpr int NT   = 3;
    constexpr int FS   = CINp * 2 + 16;
    constexpr int HS   = CH * 2 + 16;
    __shared__ __align__(16) char Fs[PPB * RP * FS];
    __shared__ __align__(16) char Hs[PPB * RP * HS];
    __shared__ int sj[PPB * RP];

    int tid = threadIdx.x;
    int lane = tid & 63, wid = tid >> 6;
    int pid0 = blockIdx.x * PPB;

    for (int r = tid; r < PPB * RP; r += 256) {
        int p = r / RP, s = r - p * RP;
        sj[r] = (s < 33) ? idx[(size_t)(pid0 + p) * 33 + s] : -1;
    }
    __syncthreads();

    constexpr int FE = PPB * RP * CINp;
    for (int e = tid; e < FE; e += 256) {
        int r = e / CINp, f = e - r * CINp;
        int p = r / RP;
        int pid = pid0 + p;
        int b = pid / N, i = pid - b * N;
        int j = sj[r];
        float v = 0.f;
        if (j >= 0 && f < CIN) {
            if (f < CXIN) {
                v = xin[((size_t)b * N + j) * CXIN + f];
            } else {
                int a = f - CXIN;
                v = __fsub_rn(pos[((size_t)b * N + j) * 3 + a],
                              pos[((size_t)b * N + i) * 3 + a]);
            }
        }
        *(short*)(Fs + (size_t)r * FS + f * 2) = bf16rne(v);
    }
    __syncthreads();

    int pw  = (PPB == 4) ? wid : 0;
    int mt0 = (PPB == 4) ? 0 : wid * MTW;
    const char* Fw = Fs + pw * RP * FS;
    char* Hw = Hs + pw * RP * HS;
    int lr = lane & 15, lg = lane >> 4;

    f4v acc[MTW][NT];
#pragma unroll
    for (int m = 0; m < MTW; m++)
#pragma unroll
        for (int nt = 0; nt < NT; nt++)
#pragma unroll
            for (int q = 0; q < 4; q++) acc[m][nt][q] = 0.f;
#pragma unroll
    for (int ks = 0; ks < KS1; ks++) {
        s8v bfr[NT];
#pragma unroll
        for (int nt = 0; nt < NT; nt++)
            bfr[nt] = *(const s8v*)(Fw + (nt * 16 + lr) * FS + (32 * ks + lg * 8) * 2);
#pragma unroll
        for (int m = 0; m < MTW; m++) {
            s8v afr = *(const s8v*)(Wpa + (((size_t)(mt0 + m) * KS1 + ks) * 64 + lane) * 8);
#pragma unroll
            for (int nt = 0; nt < NT; nt++)
                acc[m][nt] = __builtin_amdgcn_mfma_f32_16x16x32_bf16(afr, bfr[nt], acc[m][nt], 0, 0, 0);
        }
    }
#pragma unroll
    for (int m = 0; m < MTW; m++) {
        int cbase = (mt0 + m) * 16 + lg * 4;
        f4v bv = *(const f4v*)(ba + cbase);
#pragma unroll
        for (int nt = 0; nt < NT; nt++) {
            s4v hq;
#pragma unroll
            for (int q = 0; q < 4; q++)
                hq[q] = bf16rne(fmaxf(acc[m][nt][q] + bv[q], 0.f));
            *(s4v*)(Hw + (nt * 16 + lr) * HS + cbase * 2) = hq;
        }
    }
    __syncthreads();

    f4v acc2[MTW][NT];
#pragma unroll
    for (int m = 0; m < MTW; m++)
#pragma unroll
        for (int nt = 0; nt < NT; nt++)
#pragma unroll
            for (int q = 0; q < 4; q++) acc2[m][nt][q] = 0.f;
#pragma unroll
    for (int ks = 0; ks < KS2; ks++) {
        s8v bfr[NT];
#pragma unroll
        for (int nt = 0; nt < NT; nt++)
            bfr[nt] = *(const s8v*)(Hw + (nt * 16 + lr) * HS + (32 * ks + lg * 8) * 2);
#pragma unroll
        for (int m = 0; m < MTW; m++) {
            s8v afr = *(const s8v*)(Wpb + (((size_t)(mt0 + m) * KS2 + ks) * 64 + lane) * 8);
#pragma unroll
            for (int nt = 0; nt < NT; nt++)
                acc2[m][nt] = __builtin_amdgcn_mfma_f32_16x16x32_bf16(afr, bfr[nt], acc2[m][nt], 0, 0, 0);
        }
    }

    const int* sjw = sj + pw * RP;
#pragma unroll
    for (int m = 0; m < MTW; m++) {
        int cbase = (mt0 + m) * 16 + lg * 4;
        f4v bv = *(const f4v*)(bb + cbase);
        f4v vmx;
#pragma unroll
        for (int q = 0; q < 4; q++) vmx[q] = 0.f;
#pragma unroll
        for (int nt = 0; nt < NT; nt++) {
            int s = nt * 16 + lr;
            bool valid = (s < 33) && (sjw[s] >= 0);
#pragma unroll
            for (int q = 0; q < 4; q++) {
                float v = fmaxf(acc2[m][nt][q] + bv[q], 0.f);
                if (valid) vmx[q] = fmaxf(vmx[q], v);
            }
        }
#pragma unroll
        for (int off = 1; off < 16; off <<= 1)
#pragma unroll
            for (int q = 0; q < 4; q++)
                vmx[q] = fmaxf(vmx[q], __shfl_xor(vmx[q], off, 64));
        if (lr == 0) {
            int pid = pid0 + pw;
            *(f4v*)(xout + (size_t)pid * CH + cbase) = vmx;
        }
    }
}

// ---------------------------------------------------------------------------
__global__ void gather_kernel(
        const float* __restrict__ pos_in, const float* __restrict__ x_in,
        const int* __restrict__ s, int Nin, int M, int C,
        float* __restrict__ pos_out, float* __restrict__ x_out) {
    int b = blockIdx.y, m = blockIdx.x, t = threadIdx.x;
    int j = s[b * M + m];
    x_out[((size_t)b * M + m) * C + t] = x_in[((size_t)b * Nin + j) * C + t];
    if (t < 3) pos_out[((size_t)b * M + m) * 3 + t] = pos_in[((size_t)b * Nin + j) * 3 + t];
}

// ---------------------------------------------------------------------------
// Global max pool + MLP head + log_softmax (unchanged).
// ---------------------------------------------------------------------------
__global__ __launch_bounds__(256) void head_kernel(
        const float* __restrict__ x3,
        const float* __restrict__ Wl1, const float* __restrict__ bl1,
        const float* __restrict__ Wl2, const float* __restrict__ bl2,
        const float* __restrict__ Wl3, const float* __restrict__ bl3,
        float* __restrict__ out) {
    __shared__ float gbuf[256], h1[256], h2[256], h3[40];
    int b = blockIdx.x, c = threadIdx.x;
    const float* xb = x3 + (size_t)b * 256 * 256;
    float m = -INFINITY;
    for (int r = 0; r < 256; r++) m = fmaxf(m, xb[r * 256 + c]);
    gbuf[c] = m;
    __syncthreads();
    float a = bl1[c];
    for (int k = 0; k < 256; k++) a = fmaf(gbuf[k], Wl1[k * 256 + c], a);
    h1[c] = fmaxf(a, 0.f);
    __syncthreads();
    a = bl2[c];
    for (int k = 0; k < 256; k++) a = fmaf(h1[k], Wl2[k * 256 + c], a);
    h2[c] = fmaxf(a, 0.f);
    __syncthreads();
    if (c < 40) {
        a = bl3[c];
        for (int k = 0; k < 256; k++) a = fmaf(h2[k], Wl3[k * 40 + c], a);
        h3[c] = a;
    }
    __syncthreads();
    if (c < 64) {
        float v = -INFINITY;
        if (c < 40) v = h3[c];
        float mx = v;
#pragma unroll
        for (int off = 32; off >= 1; off >>= 1) mx = fmaxf(mx, __shfl_xor(mx, off, 64));
        float e = (c < 40) ? expf(__fsub_rn(v, mx)) : 0.f;
        float s = e;
#pragma unroll
        for (int off = 32; off >= 1; off >>= 1) s = __fadd_rn(s, __shfl_xor(s, off, 64));
        float ls = logf(s);
        if (c < 40) out[b * 40 + c] = __fsub_rn(__fsub_rn(v, mx), ls);
    }
}

// ---------------------------------------------------------------------------
extern "C" void kernel_launch(void* const* d_in, const int* in_sizes, int n_in,
                              void* d_out, int out_size, void* d_ws, size_t ws_size,
                              hipStream_t stream) {
    (void)in_sizes; (void)n_in; (void)out_size; (void)ws_size;
    const float* pos = (const float*)d_in[0];
    const float* W1a = (const float*)d_in[2];
    const float* b1a = (const float*)d_in[3];
    const float* W1b = (const float*)d_in[4];
    const float* b1b = (const float*)d_in[5];
    const float* W2a = (const float*)d_in[6];
    const float* b2a = (const float*)d_in[7];
    const float* W2b = (const float*)d_in[8];
    const float* b2b = (const float*)d_in[9];
    const float* W3a = (const float*)d_in[10];
    const float* b3a = (const float*)d_in[11];
    const float* W3b = (const float*)d_in[12];
    const float* b3b = (const float*)d_in[13];
    const float* Wl1 = (const float*)d_in[14];
    const float* bl1 = (const float*)d_in[15];
    const float* Wl2 = (const float*)d_in[16];
    const float* bl2 = (const float*)d_in[17];
    const float* Wl3 = (const float*)d_in[18];
    const float* bl3 = (const float*)d_in[19];
    float* out = (float*)d_out;

    const int B = 32;
    char* w = (char*)d_ws;
    auto alloc = [&](size_t bytes) -> char* {
        char* r = w;
        w += (bytes + 255) & ~(size_t)255;
        return r;
    };
    int*   idx1 = (int*)  alloc((size_t)B * 2048 * 33 * 4);
    float* x1   = (float*)alloc((size_t)B * 2048 * 64 * 4);
    int*   s1   = (int*)  alloc((size_t)B * 1024 * 4);
    float* pos2 = (float*)alloc((size_t)B * 1024 * 3 * 4);
    float* x2in = (float*)alloc((size_t)B * 1024 * 64 * 4);
    int*   idx2 = (int*)  alloc((size_t)B * 1024 * 33 * 4);
    float* x2   = (float*)alloc((size_t)B * 1024 * 128 * 4);
    int*   s2   = (int*)  alloc((size_t)B * 256 * 4);
    float* pos3 = (float*)alloc((size_t)B * 256 * 3 * 4);
    float* x3in = (float*)alloc((size_t)B * 256 * 128 * 4);
    int*   idx3 = (int*)  alloc((size_t)B * 256 * 33 * 4);
    float* x3   = (float*)alloc((size_t)B * 256 * 256 * 4);
    short* Wp1a = (short*)alloc(4  * 1 * 64 * 8 * 2);
    short* Wp1b = (short*)alloc(4  * 2 * 64 * 8 * 2);
    short* Wp2a = (short*)alloc(8  * 3 * 64 * 8 * 2);
    short* Wp2b = (short*)alloc(8  * 4 * 64 * 8 * 2);
    short* Wp3a = (short*)alloc(16 * 5 * 64 * 8 * 2);
    short* Wp3b = (short*)alloc(16 * 8 * 64 * 8 * 2);

    pack_w_kernel<<<1,  256, 0, stream>>>(W1a, Wp1a, 3,   64,  1, 256);
    pack_w_kernel<<<2,  256, 0, stream>>>(W1b, Wp1b, 64,  64,  2, 512);
    pack_w_kernel<<<6,  256, 0, stream>>>(W2a, Wp2a, 67,  128, 3, 1536);
    pack_w_kernel<<<8,  256, 0, stream>>>(W2b, Wp2b, 128, 128, 4, 2048);
    pack_w_kernel<<<20, 256, 0, stream>>>(W3a, Wp3a, 131, 256, 5, 5120);
    pack_w_kernel<<<32, 256, 0, stream>>>(W3b, Wp3b, 256, 256, 8, 8192);

    // ---- SA module 1 (2048 pts, r=0.2): radius + FPS fused (independent) ----
    radius_fps_kernel<2048, 1024><<<dim3(B, 513), 256, 0, stream>>>(
        pos, 0.04f, idx1, s1);
    conv_mfma_kernel<0, 64, 4, 2048><<<B * 2048 / 4, 256, 0, stream>>>(
        pos, nullptr, idx1, Wp1a, b1a, Wp1b, b1b, x1);
    gather_kernel<<<dim3(1024, B), 64, 0, stream>>>(pos, x1, s1, 2048, 1024, 64, pos2, x2in);

    // ---- SA module 2 (1024 pts, r=0.4): radius + FPS fused ----
    radius_fps_kernel<1024, 256><<<dim3(B, 257), 256, 0, stream>>>(
        pos2, 0.16f, idx2, s2);
    conv_mfma_kernel<64, 128, 1, 1024><<<B * 1024, 256, 0, stream>>>(
        pos2, x2in, idx2, Wp2a, b2a, Wp2b, b2b, x2);
    gather_kernel<<<dim3(256, B), 128, 0, stream>>>(pos2, x2, s2, 1024, 256, 128, pos3, x3in);

    // ---- SA module 3 (256 pts, r=1.0) ----
    radius_topk_kernel<256><<<dim3(B, 64), 256, 0, stream>>>(pos3, 1.0f, idx3);
    conv_mfma_kernel<128, 256, 1, 256><<<B * 256, 256, 0, stream>>>(
        pos3, x3in, idx3, Wp3a, b3a, Wp3b, b3b, x3);

    // ---- global pool + head ----
    head_kernel<<<B, 256, 0, stream>>>(x3, Wl1, bl1, Wl2, bl2, Wl3, bl3, out);
}